// Round 7
// baseline (141.816 us; speedup 1.0000x reference)
//
#include <hip/hip_runtime.h>

#define BB 16
#define QQ 1000
#define NH 8
#define LTOTAL 5440
#define MQ (BB*QQ)      // 16000
#define MV (BB*LTOTAL)  // 87040

typedef __bf16 bf16x8 __attribute__((ext_vector_type(8)));
typedef float  f32x4  __attribute__((ext_vector_type(4)));

template <int N> struct IC { static constexpr int v = N; };

__device__ __forceinline__ unsigned short f2bf(float f) {
  unsigned u = __builtin_bit_cast(unsigned, f);
  u += 0x7fffu + ((u >> 16) & 1u);
  return (unsigned short)(u >> 16);
}
__device__ __forceinline__ float b2f_lo(unsigned u) {
  return __builtin_bit_cast(float, u << 16);
}
__device__ __forceinline__ float b2f_hi(unsigned u) {
  return __builtin_bit_cast(float, u & 0xffff0000u);
}

__device__ __forceinline__ void gload16(const void* g, void* l) {
  __builtin_amdgcn_global_load_lds(
      (const __attribute__((address_space(1))) unsigned int*)g,
      (__attribute__((address_space(3))) unsigned int*)l, 16, 0, 0);
}

// ---------------- prep: weights -> [panel][k_octet][n] granule layout + biases --
// granule g (within panel) = k_octet*128 + n holds W[k_octet*8 .. +8][panelBase+n]
// as 8 bf16 -> B staging is a single linear 64KB copy per panel.
__global__ __launch_bounds__(256) void prep_k(const float* __restrict__ Wv,
                                              const float* __restrict__ Wo,
                                              const float* __restrict__ Wa,
                                              const float* __restrict__ Wout,
                                              const float* __restrict__ bo,
                                              const float* __restrict__ ba,
                                              unsigned short* __restrict__ WvS,  // 2 panels
                                              unsigned short* __restrict__ WcS,  // 3 panels
                                              unsigned short* __restrict__ WoS,  // 2 panels
                                              float* __restrict__ bcat) {
  int i = blockIdx.x * 256 + threadIdx.x;
  if (i < 28672) {
    const float* src;
    unsigned short* dst;
    int g, srcN;
    if (i < 8192)       { g = i;         dst = WvS; src = Wv;   srcN = 256; }
    else if (i < 20480) { g = i - 8192;  dst = WcS; src = Wo;   srcN = 256; }
    else                { g = i - 20480; dst = WoS; src = Wout; srcN = 256; }
    int panel = g >> 12, ko = (g >> 7) & 31, row = g & 127;
    int kbase = ko * 8;
    int n = panel * 128 + row;
    if (dst == WcS && panel == 2) { src = Wa; srcN = 128; n = row; }
    bf16x8 r;
#pragma unroll
    for (int e = 0; e < 8; e++) r[e] = (__bf16)src[(size_t)(kbase + e) * srcN + n];
    *(bf16x8*)(dst + (size_t)g * 8) = r;
  } else if (i < 29056) {
    int j = i - 28672;
    bcat[j] = j < 256 ? bo[j] : ba[j - 256];
  }
}

// ---------------- barrier-free MFMA GEMM -------------------------------------
// C[M,N] = A[M,256] @ W^T + bias. Block = 128x128 tile, 4 waves (2x2 of 64x64).
// Whole B panel (128 x K=256 bf16, 64KB) staged to LDS ONCE (one vmcnt + one
// barrier). K-loop: A global->reg depth-2 prefetch (precise compiler dep-waits,
// nothing for the waitcnt pass to over-drain), B from LDS, NO barriers.
// MFMA operands SWAPPED (mfma(b,a)): thread owns 1 row x 4 consecutive cols
// -> vectorized bias + dwordx2/dwordx4 stores.
template <bool AF32, bool OUTBF16>
__global__ __launch_bounds__(256) void gemm4_k(const void* __restrict__ Av,
                                               const unsigned short* __restrict__ WS,
                                               const float* __restrict__ bias,
                                               void* __restrict__ C, int M, int N) {
  constexpr int NT = 8;
  constexpr int APRE = AF32 ? 16 : 8;   // A-load instrs issued after the B stage
  __shared__ __align__(16) char lds[65536];

  int tid = threadIdx.x, wave = tid >> 6, lane = tid & 63;
  int ntiles = N >> 7;
  int mt = blockIdx.x / ntiles, nt = blockIdx.x - (blockIdx.x / ntiles) * ntiles;
  int r16 = lane & 15, kg = lane >> 4;
  int wm = wave >> 1, wn = wave & 1;

  // ---- stage whole B panel: 4096 granules x 16B, linear both sides ----
  const unsigned short* Bp = WS + (size_t)nt * 32768;
#pragma unroll
  for (int j = 0; j < 16; j++) {
    int g = j * 256 + tid;
    gload16(Bp + (size_t)g * 8, lds + (size_t)g * 16);
  }
  __builtin_amdgcn_sched_barrier(0);   // pin: B loads oldest in vmcnt order

  f32x4  ar32[2][4][2];
  bf16x8 ar16[2][4];

  const char* Ab = (const char*)Av +
      (AF32 ? (size_t)(mt * 128 + wm * 64 + r16) * 1024
            : (size_t)(mt * 128 + wm * 64 + r16) * 512);

  auto loadA = [&](auto TT, auto SS) {
    constexpr int t = decltype(TT)::v;
    constexpr int s = decltype(SS)::v;
#pragma unroll
    for (int mi = 0; mi < 4; mi++) {
      if (AF32) {
        const float* ap = (const float*)(Ab + (size_t)mi * 16 * 1024) + t * 32 + kg * 8;
        ar32[s][mi][0] = *(const f32x4*)ap;
        ar32[s][mi][1] = *(const f32x4*)(ap + 4);
      } else {
        const unsigned short* ap =
            (const unsigned short*)(Ab + (size_t)mi * 16 * 512) + t * 32 + kg * 8;
        ar16[s][mi] = *(const bf16x8*)ap;
      }
    }
  };

  loadA(IC<0>{}, IC<0>{});
  loadA(IC<1>{}, IC<1>{});
  __builtin_amdgcn_sched_barrier(0);
  asm volatile("s_waitcnt vmcnt(%0)" :: "i"(APRE) : "memory");  // B staged; A still in flight
  __builtin_amdgcn_s_barrier();

  f32x4 acc[4][4] = {};

  auto step = [&](auto TT) {
    constexpr int t = decltype(TT)::v;
    bf16x8 af[4];
#pragma unroll
    for (int mi = 0; mi < 4; mi++) {
      if (AF32) {
        f32x4 lo = ar32[t & 1][mi][0], hi = ar32[t & 1][mi][1];
        bf16x8 r;
        r[0]=(__bf16)lo[0]; r[1]=(__bf16)lo[1]; r[2]=(__bf16)lo[2]; r[3]=(__bf16)lo[3];
        r[4]=(__bf16)hi[0]; r[5]=(__bf16)hi[1]; r[6]=(__bf16)hi[2]; r[7]=(__bf16)hi[3];
        af[mi] = r;
      } else {
        af[mi] = ar16[t & 1][mi];
      }
    }
    if constexpr (t + 2 < NT) loadA(IC<t + 2>{}, IC<t & 1>{});   // depth-2 prefetch
    bf16x8 bq[4];
#pragma unroll
    for (int ni = 0; ni < 4; ni++)
      bq[ni] = *(const bf16x8*)(lds +
          ((((t * 4 + kg) * 128) + wn * 64 + ni * 16 + r16) << 4));
#pragma unroll
    for (int mi = 0; mi < 4; mi++)
#pragma unroll
      for (int ni = 0; ni < 4; ni++)
        acc[mi][ni] = __builtin_amdgcn_mfma_f32_16x16x32_bf16(bq[ni], af[mi], acc[mi][ni], 0, 0, 0);
  };
  step(IC<0>{}); step(IC<1>{}); step(IC<2>{}); step(IC<3>{});
  step(IC<4>{}); step(IC<5>{}); step(IC<6>{}); step(IC<7>{});

  // ---- epilogue: swapped layout -> row = ..+r16, cols = ..+kg*4+{0..3} ----
  int rowBase = mt * 128 + wm * 64;
  int colBase = nt * 128 + wn * 64;
#pragma unroll
  for (int ni = 0; ni < 4; ni++) {
    int col = colBase + ni * 16 + kg * 4;
    f32x4 bs = *(const f32x4*)(bias + col);
#pragma unroll
    for (int mi = 0; mi < 4; mi++) {
      int row = rowBase + mi * 16 + r16;
      f32x4 v = acc[mi][ni] + bs;
      if (OUTBF16) {
        uint2 st;
        st.x = f2bf(v[0]) | ((unsigned)f2bf(v[1]) << 16);
        st.y = f2bf(v[2]) | ((unsigned)f2bf(v[3]) << 16);
        *(uint2*)((unsigned short*)C + (size_t)row * N + col) = st;
      } else {
        *(f32x4*)((float*)C + (size_t)row * N + col) = v;
      }
    }
  }
}

// ---------------- sampling: softmax + bilinear gather-accumulate ----------------
// 32 lanes per (b,q); lane owns 8 channels of one head. Per level: compute all
// 16 (weight, offset) corner descriptors, THEN issue all 16 uint4 gathers, THEN
// FMA — 16-deep MLP per wave. __launch_bounds__(256,3) for load-queue headroom.
__global__ __launch_bounds__(256, 3) void sample_k(const float* __restrict__ offattn, // [MQ,384]
                                                   const float* __restrict__ refp,    // [B,Q,4,2]
                                                   const unsigned short* __restrict__ value,
                                                   unsigned short* __restrict__ inter) { // [MQ,256]
  int t  = blockIdx.x * 256 + threadIdx.x;
  int bq = t >> 5;
  int h  = (t >> 2) & 7;
  int c0 = (t & 3) << 3;
  int b  = bq / QQ;

  const float* base = offattn + (size_t)bq * 384;

  float lg[16];
  const float4* ab4 = (const float4*)(base + 256 + h * 16);
#pragma unroll
  for (int i = 0; i < 4; i++) {
    float4 v = ab4[i];
    lg[4*i] = v.x; lg[4*i+1] = v.y; lg[4*i+2] = v.z; lg[4*i+3] = v.w;
  }
  float m = -1e30f;
#pragma unroll
  for (int i = 0; i < 16; i++) m = fmaxf(m, lg[i]);
  float s = 0.f;
#pragma unroll
  for (int i = 0; i < 16; i++) { lg[i] = __expf(lg[i] - m); s += lg[i]; }
  float inv = 1.0f / s;

  float4 r01 = ((const float4*)(refp + (size_t)bq * 8))[0];
  float4 r23 = ((const float4*)(refp + (size_t)bq * 8))[1];
  float rxs[4] = {r01.x, r01.z, r23.x, r23.z};
  float rys[4] = {r01.y, r01.w, r23.y, r23.w};

  const unsigned short* vb = value + (size_t)b * (LTOTAL * 256) + h * 32 + c0;
  const int startL[4] = {0, 4096, 5120, 5376};

  float acc[8] = {};
#pragma unroll
  for (int lvl = 0; lvl < 4; lvl++) {
    int   Wi = 64 >> lvl;
    float Wf = (float)Wi;
    float px = rxs[lvl] * Wf - 0.5f;
    float py = rys[lvl] * Wf - 0.5f;
    const unsigned short* vl = vb + (size_t)startL[lvl] * 256;

    const float4* ob4 = (const float4*)(base + h * 32 + lvl * 8);
    float4 o01 = ob4[0], o23 = ob4[1];
    float oxs[4] = {o01.x, o01.z, o23.x, o23.z};
    float oys[4] = {o01.y, o01.w, o23.y, o23.w};

    float cw[16];
    int   coff[16];
#pragma unroll
    for (int pt = 0; pt < 4; pt++) {
      float wa = lg[lvl * 4 + pt] * inv;
      float x = px + oxs[pt];
      float y = py + oys[pt];
      float xf = floorf(x), yf = floorf(y);
      float lx = x - xf, ly = y - yf;
      int x0 = (int)xf, y0 = (int)yf;
      float wx[2] = {1.f - lx, lx};
      float wy[2] = {1.f - ly, ly};
#pragma unroll
      for (int cy = 0; cy < 2; cy++) {
        int Y = y0 + cy;
        bool vy = (unsigned)Y < (unsigned)Wi;
        int Yc = min(max(Y, 0), Wi - 1);
#pragma unroll
        for (int cx = 0; cx < 2; cx++) {
          int X = x0 + cx;
          bool vx = (unsigned)X < (unsigned)Wi;
          int Xc = min(max(X, 0), Wi - 1);
          int c = pt * 4 + cy * 2 + cx;
          cw[c]   = (vx && vy) ? wa * wy[cy] * wx[cx] : 0.f;
          coff[c] = (Yc * Wi + Xc) * 256;
        }
      }
    }
    uint4 raw[16];
#pragma unroll
    for (int c = 0; c < 16; c++) raw[c] = *(const uint4*)(vl + coff[c]);
#pragma unroll
    for (int c = 0; c < 16; c++) {
      float w = cw[c];
      acc[0] += w * b2f_lo(raw[c].x); acc[1] += w * b2f_hi(raw[c].x);
      acc[2] += w * b2f_lo(raw[c].y); acc[3] += w * b2f_hi(raw[c].y);
      acc[4] += w * b2f_lo(raw[c].z); acc[5] += w * b2f_hi(raw[c].z);
      acc[6] += w * b2f_lo(raw[c].w); acc[7] += w * b2f_hi(raw[c].w);
    }
  }

  unsigned o0 = f2bf(acc[0]) | ((unsigned)f2bf(acc[1]) << 16);
  unsigned o1 = f2bf(acc[2]) | ((unsigned)f2bf(acc[3]) << 16);
  unsigned o2 = f2bf(acc[4]) | ((unsigned)f2bf(acc[5]) << 16);
  unsigned o3 = f2bf(acc[6]) | ((unsigned)f2bf(acc[7]) << 16);
  uint4 st = {o0, o1, o2, o3};
  *(uint4*)(inter + (size_t)bq * 256 + h * 32 + c0) = st;
}

extern "C" void kernel_launch(void* const* d_in, const int* in_sizes, int n_in,
                              void* d_out, int out_size, void* d_ws, size_t ws_size,
                              hipStream_t stream) {
  const float* query  = (const float*)d_in[0];
  const float* refp   = (const float*)d_in[1];
  const float* inputf = (const float*)d_in[2];
  const float* Wv   = (const float*)d_in[5];
  const float* bv   = (const float*)d_in[6];
  const float* Wo   = (const float*)d_in[7];
  const float* bo   = (const float*)d_in[8];
  const float* Wa   = (const float*)d_in[9];
  const float* ba   = (const float*)d_in[10];
  const float* Wout = (const float*)d_in[11];
  const float* bout = (const float*)d_in[12];

  char* p = (char*)d_ws;
  auto alloc = [&](size_t bytes) -> char* {
    char* r = p;
    p += (bytes + 255) & ~(size_t)255;
    return r;
  };
  unsigned short* val   = (unsigned short*)alloc((size_t)MV * 256 * 2);
  unsigned short* WvS   = (unsigned short*)alloc(2 * 4096 * 8 * 2);
  unsigned short* WcS   = (unsigned short*)alloc(3 * 4096 * 8 * 2);
  unsigned short* WoS   = (unsigned short*)alloc(2 * 4096 * 8 * 2);
  float*          bcat  = (float*)alloc(384 * 4);
  float*          offattn = (float*)alloc((size_t)MQ * 384 * 4);
  unsigned short* inter = (unsigned short*)alloc((size_t)MQ * 256 * 2);

  prep_k<<<114, 256, 0, stream>>>(Wv, Wo, Wa, Wout, bo, ba, WvS, WcS, WoS, bcat);

  // value = input_flatten @ Wv + bv (fp32 A, fused cvt) -> bf16 [MV,256]
  gemm4_k<true, true><<<(MV / 128) * 2, 256, 0, stream>>>(
      (const void*)inputf, WvS, bv, val, MV, 256);
  // offattn = query @ [Wo|Wa] + [bo|ba] -> fp32 [MQ,384]
  gemm4_k<true, false><<<(MQ / 128) * 3, 256, 0, stream>>>(
      (const void*)query, WcS, bcat, offattn, MQ, 384);
  // sampling -> inter bf16 [MQ,256]
  sample_k<<<MQ * 32 / 256, 256, 0, stream>>>(offattn, refp, val, inter);
  // out = inter @ Wout + bout -> fp32 d_out
  gemm4_k<false, false><<<(MQ / 128) * 2, 256, 0, stream>>>(
      (const void*)inter, WoS, bout, (float*)d_out, MQ, 256);
}

// Round 8
// 119.151 us; speedup vs baseline: 1.1902x; 1.1902x over previous
//
#include <hip/hip_runtime.h>

#define BB 16
#define QQ 1000
#define NH 8
#define LTOTAL 5440
#define MQ (BB*QQ)      // 16000
#define MV (BB*LTOTAL)  // 87040

typedef __bf16 bf16x8 __attribute__((ext_vector_type(8)));
typedef float  f32x4  __attribute__((ext_vector_type(4)));

template <int N> struct IC { static constexpr int v = N; };

__device__ __forceinline__ unsigned short f2bf(float f) {
  unsigned u = __builtin_bit_cast(unsigned, f);
  u += 0x7fffu + ((u >> 16) & 1u);
  return (unsigned short)(u >> 16);
}
__device__ __forceinline__ float b2f_lo(unsigned u) {
  return __builtin_bit_cast(float, u << 16);
}
__device__ __forceinline__ float b2f_hi(unsigned u) {
  return __builtin_bit_cast(float, u & 0xffff0000u);
}

__device__ __forceinline__ void gload16(const void* g, void* l) {
  __builtin_amdgcn_global_load_lds(
      (const __attribute__((address_space(1))) unsigned int*)g,
      (__attribute__((address_space(3))) unsigned int*)l, 16, 0, 0);
}

// lgkmcnt(0) + raw barrier; vmcnt deliberately NOT drained.
__device__ __forceinline__ void pipe_barrier() {
  asm volatile("s_waitcnt lgkmcnt(0)" ::: "memory");
  __builtin_amdgcn_sched_barrier(0);
  __builtin_amdgcn_s_barrier();
  __builtin_amdgcn_sched_barrier(0);
}

// ---------------- prep: weights -> [panel][k_octet][n] granule layout + biases --
__global__ __launch_bounds__(256) void prep_k(const float* __restrict__ Wv,
                                              const float* __restrict__ Wo,
                                              const float* __restrict__ Wa,
                                              const float* __restrict__ Wout,
                                              const float* __restrict__ bo,
                                              const float* __restrict__ ba,
                                              unsigned short* __restrict__ WvS,  // 2 panels
                                              unsigned short* __restrict__ WcS,  // 3 panels
                                              unsigned short* __restrict__ WoS,  // 2 panels
                                              float* __restrict__ bcat) {
  int i = blockIdx.x * 256 + threadIdx.x;
  if (i < 28672) {
    const float* src;
    unsigned short* dst;
    int g, srcN;
    if (i < 8192)       { g = i;         dst = WvS; src = Wv;   srcN = 256; }
    else if (i < 20480) { g = i - 8192;  dst = WcS; src = Wo;   srcN = 256; }
    else                { g = i - 20480; dst = WoS; src = Wout; srcN = 256; }
    int panel = g >> 12, ko = (g >> 7) & 31, row = g & 127;
    int kbase = ko * 8;
    int n = panel * 128 + row;
    if (dst == WcS && panel == 2) { src = Wa; srcN = 128; n = row; }
    bf16x8 r;
#pragma unroll
    for (int e = 0; e < 8; e++) r[e] = (__bf16)src[(size_t)(kbase + e) * srcN + n];
    *(bf16x8*)(dst + (size_t)g * 8) = r;
  } else if (i < 29056) {
    int j = i - 28672;
    bcat[j] = j < 256 ? bo[j] : ba[j - 256];
  }
}

// ---------------- gemm3 (R6, verbatim): 128x128, 256 thr, in-loop DMA pipeline --
template <bool AF32, bool OUTBF16>
__global__ __launch_bounds__(256) void gemm3_k(const void* __restrict__ Av,
                                               const unsigned short* __restrict__ WS,
                                               const float* __restrict__ bias,
                                               void* __restrict__ C, int M, int N) {
  constexpr int K = 256, NT = 8;
  constexpr int STEADY = AF32 ? 6 : 4;
  constexpr int ASL = AF32 ? 2 : 3;
  __shared__ char lds[(ASL + 3) * 8192];
  char* As = lds;
  char* Bs = lds + ASL * 8192;

  int tid = threadIdx.x, wave = tid >> 6, lane = tid & 63;
  int ntiles = N >> 7;
  int mt = blockIdx.x / ntiles, nt = blockIdx.x - (blockIdx.x / ntiles) * ntiles;
  int r16 = lane & 15, kg = lane >> 4;
  int wm = wave >> 1, wn = wave & 1;
  int arow = tid >> 1, ahalf = tid & 1;

  const unsigned short* Bpanel = WS + (size_t)nt * (NT * 512 * 8);
  const unsigned short* Apanel = (const unsigned short*)Av + (size_t)mt * (NT * 512 * 8);
  const float* Ag32 = (const float*)Av + (size_t)(mt * 128 + arow) * K + ahalf * 16;

  f32x4 ar[2][4];
  f32x4 acc[4][4] = {};

  auto stageB = [&](int s) {
    char* Bd = Bs + (s % 3) * 8192;
    const unsigned short* sp = Bpanel + (size_t)s * 512 * 8;
#pragma unroll
    for (int j = 0; j < 2; j++) {
      int f = (j * 4 + wave) * 64 + lane;
      gload16(sp + f * 8, Bd + f * 16);
    }
  };
  auto stageA16 = [&](int s) {
    char* Ad = As + (s % 3) * 8192;
    const unsigned short* sp = Apanel + (size_t)s * 512 * 8;
#pragma unroll
    for (int j = 0; j < 2; j++) {
      int f = (j * 4 + wave) * 64 + lane;
      gload16(sp + f * 8, Ad + f * 16);
    }
  };
  auto loadA32 = [&](int s, f32x4* r) {
    const float* sp = Ag32 + s * 32;
    r[0] = *(const f32x4*)(sp);
    r[1] = *(const f32x4*)(sp + 4);
    r[2] = *(const f32x4*)(sp + 8);
    r[3] = *(const f32x4*)(sp + 12);
  };
  auto writeA32 = [&](int slot, f32x4* r) {
    bf16x8 g0, g1;
    g0[0]=(__bf16)r[0][0]; g0[1]=(__bf16)r[0][1]; g0[2]=(__bf16)r[0][2]; g0[3]=(__bf16)r[0][3];
    g0[4]=(__bf16)r[1][0]; g0[5]=(__bf16)r[1][1]; g0[6]=(__bf16)r[1][2]; g0[7]=(__bf16)r[1][3];
    g1[0]=(__bf16)r[2][0]; g1[1]=(__bf16)r[2][1]; g1[2]=(__bf16)r[2][2]; g1[3]=(__bf16)r[2][3];
    g1[4]=(__bf16)r[3][0]; g1[5]=(__bf16)r[3][1]; g1[6]=(__bf16)r[3][2]; g1[7]=(__bf16)r[3][3];
    char* Ad = As + slot * 8192;
    int u0 = ahalf * 2;
    *(bf16x8*)(Ad + (((u0    ) * 128 + arow) << 4)) = g0;
    *(bf16x8*)(Ad + (((u0 + 1) * 128 + arow) << 4)) = g1;
  };
  auto compute = [&](int sa, int sb) {
    const char* Ad = As + sa * 8192;
    const char* Bd = Bs + sb * 8192;
    bf16x8 af[4], bq[4];
#pragma unroll
    for (int mi = 0; mi < 4; mi++) {
      int row = wm * 64 + mi * 16 + r16;
      af[mi] = *(const bf16x8*)(Ad + ((kg * 128 + row) << 4));
    }
#pragma unroll
    for (int ni = 0; ni < 4; ni++) {
      int row = wn * 64 + ni * 16 + r16;
      bq[ni] = *(const bf16x8*)(Bd + ((kg * 128 + row) << 4));
    }
#pragma unroll
    for (int mi = 0; mi < 4; mi++)
#pragma unroll
      for (int ni = 0; ni < 4; ni++)
        acc[mi][ni] = __builtin_amdgcn_mfma_f32_16x16x32_bf16(af[mi], bq[ni], acc[mi][ni], 0, 0, 0);
  };

  if (AF32) { loadA32(0, ar[0]); stageB(0); loadA32(1, ar[1]); stageB(1); }
  else      { stageA16(0); stageB(0); stageA16(1); stageB(1); }
  asm volatile("s_waitcnt vmcnt(%0)" :: "i"(STEADY) : "memory");
  if (AF32) writeA32(0, ar[0]);
  pipe_barrier();

  auto step = [&](auto TC) {
    constexpr int t = decltype(TC)::v;
    if constexpr (t + 2 < NT) {
      if (AF32) loadA32(t + 2, ar[(t + 2) & 1]);
      else      stageA16(t + 2);
      stageB(t + 2);
    }
    compute(AF32 ? (t & 1) : (t % 3), t % 3);
    if constexpr (t + 1 < NT) {
      if constexpr (t + 2 < NT)
        asm volatile("s_waitcnt vmcnt(%0)" :: "i"(STEADY) : "memory");
      else
        asm volatile("s_waitcnt vmcnt(0)" ::: "memory");
      if (AF32) writeA32((t + 1) & 1, ar[(t + 1) & 1]);
      pipe_barrier();
    }
  };
  step(IC<0>{}); step(IC<1>{}); step(IC<2>{}); step(IC<3>{});
  step(IC<4>{}); step(IC<5>{}); step(IC<6>{}); step(IC<7>{});

  int row0 = mt * 128 + wm * 64 + kg * 4;
  int col0 = nt * 128 + wn * 64 + r16;
#pragma unroll
  for (int ni = 0; ni < 4; ni++) {
    int col = col0 + ni * 16;
    float bs = bias[col];
#pragma unroll
    for (int mi = 0; mi < 4; mi++) {
#pragma unroll
      for (int j = 0; j < 4; j++) {
        int row = row0 + mi * 16 + j;
        float v = acc[mi][ni][j] + bs;
        if (OUTBF16) ((unsigned short*)C)[(size_t)row * N + col] = f2bf(v);
        else         ((float*)C)[(size_t)row * N + col] = v;
      }
    }
  }
}

// ---------------- gemm5: 256x128 tile, 512 thr / 8 waves, 2 blocks/CU ----------
// Same in-loop-DMA counted-vmcnt raw-barrier schedule as gemm3, but 2x occupancy
// (56KB LDS, VGPR capped at 128 via launch_bounds) and 2x MFMA per staged byte.
// fp32 A only, bf16 out. Swapped-operand MFMA -> vectorized epilogue (from R7).
__global__ __launch_bounds__(512, 4) void gemm5_k(const float* __restrict__ Av,
                                                  const unsigned short* __restrict__ WS,
                                                  const float* __restrict__ bias,
                                                  unsigned short* __restrict__ C,
                                                  int M, int N) {
  constexpr int K = 256, NT = 8;
  constexpr int STEADY = 5;   // A(t+2)=4 + B(t+2)=1 newer than stage(t+1)
  __shared__ __align__(16) char lds[2 * 16384 + 3 * 8192];   // 56KB
  char* As = lds;
  char* Bs = lds + 32768;

  int tid = threadIdx.x, wave = tid >> 6, lane = tid & 63;
  int mt = blockIdx.x >> 1, nt = blockIdx.x & 1;
  int r16 = lane & 15, kg = lane >> 4;
  int wm = wave >> 1, wn = wave & 1;
  int arow = tid >> 1, ahalf = tid & 1;

  const unsigned short* Bp = WS + (size_t)nt * (NT * 512 * 8);
  const float* Ag32 = Av + (size_t)(mt * 256 + arow) * K + ahalf * 16;

  f32x4 ar[2][4];
  f32x4 acc[4][4] = {};

  auto stageB = [&](int s) {
    gload16(Bp + ((size_t)s * 512 + tid) * 8, Bs + (s % 3) * 8192 + tid * 16);
  };
  auto loadA32 = [&](int s, f32x4* r) {
    const float* sp = Ag32 + s * 32;
    r[0] = *(const f32x4*)(sp);
    r[1] = *(const f32x4*)(sp + 4);
    r[2] = *(const f32x4*)(sp + 8);
    r[3] = *(const f32x4*)(sp + 12);
  };
  auto writeA32 = [&](int slot, f32x4* r) {
    bf16x8 g0, g1;
    g0[0]=(__bf16)r[0][0]; g0[1]=(__bf16)r[0][1]; g0[2]=(__bf16)r[0][2]; g0[3]=(__bf16)r[0][3];
    g0[4]=(__bf16)r[1][0]; g0[5]=(__bf16)r[1][1]; g0[6]=(__bf16)r[1][2]; g0[7]=(__bf16)r[1][3];
    g1[0]=(__bf16)r[2][0]; g1[1]=(__bf16)r[2][1]; g1[2]=(__bf16)r[2][2]; g1[3]=(__bf16)r[2][3];
    g1[4]=(__bf16)r[3][0]; g1[5]=(__bf16)r[3][1]; g1[6]=(__bf16)r[3][2]; g1[7]=(__bf16)r[3][3];
    char* Ad = As + slot * 16384;
    int u0 = ahalf * 2;
    *(bf16x8*)(Ad + (((u0    ) * 256 + arow) << 4)) = g0;
    *(bf16x8*)(Ad + (((u0 + 1) * 256 + arow) << 4)) = g1;
  };
  auto compute = [&](int t) {
    const char* Ad = As + (t & 1) * 16384;
    const char* Bd = Bs + (t % 3) * 8192;
    bf16x8 af[4], bq[4];
#pragma unroll
    for (int mi = 0; mi < 4; mi++) {
      int row = wm * 64 + mi * 16 + r16;
      af[mi] = *(const bf16x8*)(Ad + ((kg * 256 + row) << 4));
    }
#pragma unroll
    for (int ni = 0; ni < 4; ni++) {
      int row = wn * 64 + ni * 16 + r16;
      bq[ni] = *(const bf16x8*)(Bd + ((kg * 128 + row) << 4));
    }
#pragma unroll
    for (int mi = 0; mi < 4; mi++)
#pragma unroll
      for (int ni = 0; ni < 4; ni++)
        acc[mi][ni] = __builtin_amdgcn_mfma_f32_16x16x32_bf16(bq[ni], af[mi], acc[mi][ni], 0, 0, 0);
  };

  loadA32(0, ar[0]); stageB(0); loadA32(1, ar[1]); stageB(1);
  asm volatile("s_waitcnt vmcnt(%0)" :: "i"(STEADY) : "memory");
  writeA32(0, ar[0]);
  pipe_barrier();

  auto step = [&](auto TC) {
    constexpr int t = decltype(TC)::v;
    if constexpr (t + 2 < NT) {
      loadA32(t + 2, ar[(t + 2) & 1]);
      stageB(t + 2);
    }
    compute(t);
    if constexpr (t + 1 < NT) {
      if constexpr (t + 2 < NT)
        asm volatile("s_waitcnt vmcnt(%0)" :: "i"(STEADY) : "memory");
      else
        asm volatile("s_waitcnt vmcnt(0)" ::: "memory");
      writeA32((t + 1) & 1, ar[(t + 1) & 1]);
      pipe_barrier();
    }
  };
  step(IC<0>{}); step(IC<1>{}); step(IC<2>{}); step(IC<3>{});
  step(IC<4>{}); step(IC<5>{}); step(IC<6>{}); step(IC<7>{});

  // swapped-operand epilogue (verified in R7): row from af, 4 consecutive cols
  int rowBase = mt * 256 + wm * 64;
  int colBase = nt * 128 + wn * 64;
#pragma unroll
  for (int ni = 0; ni < 4; ni++) {
    int col = colBase + ni * 16 + kg * 4;
    f32x4 bs = *(const f32x4*)(bias + col);
#pragma unroll
    for (int mi = 0; mi < 4; mi++) {
      int row = rowBase + mi * 16 + r16;
      f32x4 v = acc[mi][ni] + bs;
      uint2 st;
      st.x = f2bf(v[0]) | ((unsigned)f2bf(v[1]) << 16);
      st.y = f2bf(v[2]) | ((unsigned)f2bf(v[3]) << 16);
      *(uint2*)(C + (size_t)row * N + col) = st;
    }
  }
}

// ---------------- sampling (R6 verbatim): batched 16-gather MLP, staged store --
__global__ __launch_bounds__(256, 3) void sample_k(const float* __restrict__ offattn, // [MQ,384]
                                                   const float* __restrict__ refp,    // [B,Q,4,2]
                                                   const unsigned short* __restrict__ value,
                                                   unsigned short* __restrict__ interS) {
  int t  = blockIdx.x * 256 + threadIdx.x;
  int bq = t >> 5;
  int h  = (t >> 2) & 7;
  int c0 = (t & 3) << 3;
  int b  = bq / QQ;

  const float* base = offattn + (size_t)bq * 384;

  float lg[16];
  const float4* ab4 = (const float4*)(base + 256 + h * 16);
#pragma unroll
  for (int i = 0; i < 4; i++) {
    float4 v = ab4[i];
    lg[4*i] = v.x; lg[4*i+1] = v.y; lg[4*i+2] = v.z; lg[4*i+3] = v.w;
  }
  float m = -1e30f;
#pragma unroll
  for (int i = 0; i < 16; i++) m = fmaxf(m, lg[i]);
  float s = 0.f;
#pragma unroll
  for (int i = 0; i < 16; i++) { lg[i] = __expf(lg[i] - m); s += lg[i]; }
  float inv = 1.0f / s;

  float4 r01 = ((const float4*)(refp + (size_t)bq * 8))[0];
  float4 r23 = ((const float4*)(refp + (size_t)bq * 8))[1];
  float rxs[4] = {r01.x, r01.z, r23.x, r23.z};
  float rys[4] = {r01.y, r01.w, r23.y, r23.w};

  const unsigned short* vb = value + (size_t)b * (LTOTAL * 256) + h * 32 + c0;
  const int startL[4] = {0, 4096, 5120, 5376};

  float acc[8] = {};
#pragma unroll
  for (int lvl = 0; lvl < 4; lvl++) {
    int   Wi = 64 >> lvl;
    float Wf = (float)Wi;
    float px = rxs[lvl] * Wf - 0.5f;
    float py = rys[lvl] * Wf - 0.5f;
    const unsigned short* vl = vb + (size_t)startL[lvl] * 256;

    const float4* ob4 = (const float4*)(base + h * 32 + lvl * 8);
    float4 o01 = ob4[0], o23 = ob4[1];
    float oxs[4] = {o01.x, o01.z, o23.x, o23.z};
    float oys[4] = {o01.y, o01.w, o23.y, o23.w};

    float cw[16];
    int   coff[16];
#pragma unroll
    for (int pt = 0; pt < 4; pt++) {
      float wa = lg[lvl * 4 + pt] * inv;
      float x = px + oxs[pt];
      float y = py + oys[pt];
      float xf = floorf(x), yf = floorf(y);
      float lx = x - xf, ly = y - yf;
      int x0 = (int)xf, y0 = (int)yf;
      float wx[2] = {1.f - lx, lx};
      float wy[2] = {1.f - ly, ly};
#pragma unroll
      for (int cy = 0; cy < 2; cy++) {
        int Y = y0 + cy;
        bool vy = (unsigned)Y < (unsigned)Wi;
        int Yc = min(max(Y, 0), Wi - 1);
#pragma unroll
        for (int cx = 0; cx < 2; cx++) {
          int X = x0 + cx;
          bool vx = (unsigned)X < (unsigned)Wi;
          int Xc = min(max(X, 0), Wi - 1);
          int c = pt * 4 + cy * 2 + cx;
          cw[c]   = (vx && vy) ? wa * wy[cy] * wx[cx] : 0.f;
          coff[c] = (Yc * Wi + Xc) * 256;
        }
      }
    }
    uint4 raw[16];
#pragma unroll
    for (int c = 0; c < 16; c++) raw[c] = *(const uint4*)(vl + coff[c]);
#pragma unroll
    for (int c = 0; c < 16; c++) {
      float w = cw[c];
      acc[0] += w * b2f_lo(raw[c].x); acc[1] += w * b2f_hi(raw[c].x);
      acc[2] += w * b2f_lo(raw[c].y); acc[3] += w * b2f_hi(raw[c].y);
      acc[4] += w * b2f_lo(raw[c].z); acc[5] += w * b2f_hi(raw[c].z);
      acc[6] += w * b2f_lo(raw[c].w); acc[7] += w * b2f_hi(raw[c].w);
    }
  }

  unsigned o0 = f2bf(acc[0]) | ((unsigned)f2bf(acc[1]) << 16);
  unsigned o1 = f2bf(acc[2]) | ((unsigned)f2bf(acc[3]) << 16);
  unsigned o2 = f2bf(acc[4]) | ((unsigned)f2bf(acc[5]) << 16);
  unsigned o3 = f2bf(acc[6]) | ((unsigned)f2bf(acc[7]) << 16);
  uint4 st = {o0, o1, o2, o3};

  // staged layout: tile = bq>>7, row = bq&127, stage = h, u = c0>>3
  int mtile = bq >> 7, row = bq & 127;
  size_t goff = (((size_t)(mtile * 8 + h)) * 512 + (c0 >> 3) * 128 + row) * 8;
  *(uint4*)(interS + goff) = st;
}

extern "C" void kernel_launch(void* const* d_in, const int* in_sizes, int n_in,
                              void* d_out, int out_size, void* d_ws, size_t ws_size,
                              hipStream_t stream) {
  const float* query  = (const float*)d_in[0];
  const float* refp   = (const float*)d_in[1];
  const float* inputf = (const float*)d_in[2];
  const float* Wv   = (const float*)d_in[5];
  const float* bv   = (const float*)d_in[6];
  const float* Wo   = (const float*)d_in[7];
  const float* bo   = (const float*)d_in[8];
  const float* Wa   = (const float*)d_in[9];
  const float* ba   = (const float*)d_in[10];
  const float* Wout = (const float*)d_in[11];
  const float* bout = (const float*)d_in[12];

  char* p = (char*)d_ws;
  auto alloc = [&](size_t bytes) -> char* {
    char* r = p;
    p += (bytes + 255) & ~(size_t)255;
    return r;
  };
  unsigned short* val   = (unsigned short*)alloc((size_t)MV * 256 * 2);
  unsigned short* WvS   = (unsigned short*)alloc(2 * 4096 * 8 * 2);
  unsigned short* WcS   = (unsigned short*)alloc(3 * 4096 * 8 * 2);
  unsigned short* WoS   = (unsigned short*)alloc(2 * 4096 * 8 * 2);
  float*          bcat  = (float*)alloc(384 * 4);
  float*          offattn = (float*)alloc((size_t)MQ * 384 * 4);
  unsigned short* interS = (unsigned short*)alloc((size_t)MQ * 256 * 2);

  prep_k<<<114, 256, 0, stream>>>(Wv, Wo, Wa, Wout, bo, ba, WvS, WcS, WoS, bcat);

  // value = input_flatten @ Wv + bv -> bf16 [MV,256]  (256-row tiles, 512 thr)
  gemm5_k<<<(MV / 256) * 2, 512, 0, stream>>>(inputf, WvS, bv, val, MV, 256);
  // offattn = query @ [Wo|Wa] + [bo|ba] -> fp32 [MQ,384]
  gemm3_k<true, false><<<(MQ / 128) * 3, 256, 0, stream>>>(
      (const void*)query, WcS, bcat, offattn, MQ, 384);
  // sampling -> interS (staged bf16)
  sample_k<<<MQ * 32 / 256, 256, 0, stream>>>(offattn, refp, val, interS);
  // out = interS @ Wout + bout -> fp32 d_out
  gemm3_k<false, false><<<(MQ / 128) * 2, 256, 0, stream>>>(
      (const void*)interS, WoS, bout, (float*)d_out, MQ, 256);
}

// Round 9
// 115.838 us; speedup vs baseline: 1.2243x; 1.0286x over previous
//
#include <hip/hip_runtime.h>

#define BB 16
#define QQ 1000
#define NH 8
#define LTOTAL 5440
#define MQ (BB*QQ)      // 16000
#define MV (BB*LTOTAL)  // 87040
#define NVBLK ((MV/128)*2)   // 1360 value-GEMM blocks
#define NOBLK ((MQ/128)*3)   // 375 offattn-GEMM blocks

typedef __bf16 bf16x8 __attribute__((ext_vector_type(8)));
typedef float  f32x4  __attribute__((ext_vector_type(4)));

template <int N> struct IC { static constexpr int v = N; };

__device__ __forceinline__ unsigned short f2bf(float f) {
  unsigned u = __builtin_bit_cast(unsigned, f);
  u += 0x7fffu + ((u >> 16) & 1u);
  return (unsigned short)(u >> 16);
}
__device__ __forceinline__ float b2f_lo(unsigned u) {
  return __builtin_bit_cast(float, u << 16);
}
__device__ __forceinline__ float b2f_hi(unsigned u) {
  return __builtin_bit_cast(float, u & 0xffff0000u);
}

__device__ __forceinline__ void gload16(const void* g, void* l) {
  __builtin_amdgcn_global_load_lds(
      (const __attribute__((address_space(1))) unsigned int*)g,
      (__attribute__((address_space(3))) unsigned int*)l, 16, 0, 0);
}

// lgkmcnt(0) + raw barrier; vmcnt deliberately NOT drained.
__device__ __forceinline__ void pipe_barrier() {
  asm volatile("s_waitcnt lgkmcnt(0)" ::: "memory");
  __builtin_amdgcn_sched_barrier(0);
  __builtin_amdgcn_s_barrier();
  __builtin_amdgcn_sched_barrier(0);
}

// ---------------- prep: weights -> [panel][k_octet][n] granule layout + biases --
__global__ __launch_bounds__(256) void prep_k(const float* __restrict__ Wv,
                                              const float* __restrict__ Wo,
                                              const float* __restrict__ Wa,
                                              const float* __restrict__ Wout,
                                              const float* __restrict__ bo,
                                              const float* __restrict__ ba,
                                              unsigned short* __restrict__ WvS,  // 2 panels
                                              unsigned short* __restrict__ WcS,  // 3 panels
                                              unsigned short* __restrict__ WoS,  // 2 panels
                                              float* __restrict__ bcat) {
  int i = blockIdx.x * 256 + threadIdx.x;
  if (i < 28672) {
    const float* src;
    unsigned short* dst;
    int g, srcN;
    if (i < 8192)       { g = i;         dst = WvS; src = Wv;   srcN = 256; }
    else if (i < 20480) { g = i - 8192;  dst = WcS; src = Wo;   srcN = 256; }
    else                { g = i - 20480; dst = WoS; src = Wout; srcN = 256; }
    int panel = g >> 12, ko = (g >> 7) & 31, row = g & 127;
    int kbase = ko * 8;
    int n = panel * 128 + row;
    if (dst == WcS && panel == 2) { src = Wa; srcN = 128; n = row; }
    bf16x8 r;
#pragma unroll
    for (int e = 0; e < 8; e++) r[e] = (__bf16)src[(size_t)(kbase + e) * srcN + n];
    *(bf16x8*)(dst + (size_t)g * 8) = r;
  } else if (i < 29056) {
    int j = i - 28672;
    bcat[j] = j < 256 ? bo[j] : ba[j - 256];
  }
}

// ---------------- fused value+offattn GEMM (both fp32-A), one dispatch ---------
// blockIdx < NVBLK : value = input_flatten @ WvS + bv -> bf16 [MV,256]
// else             : offattn = query @ WcS + bcat     -> fp32 [MQ,384]
// Independent outputs; offattn blocks fill the value GEMM's latency stalls.
// Schedule = gemm3 (R6): in-loop LDS-DMA for B, reg-staged fp32 A, counted
// vmcnt, raw barriers.
__global__ __launch_bounds__(256) void gemmf_k(const float* __restrict__ Aval,
                                               const float* __restrict__ Aoff,
                                               const unsigned short* __restrict__ WvS,
                                               const unsigned short* __restrict__ WcS,
                                               const float* __restrict__ bv,
                                               const float* __restrict__ bcat,
                                               unsigned short* __restrict__ Cval,
                                               float* __restrict__ Coff) {
  constexpr int K = 256, NT = 8;
  constexpr int STEADY = 6;
  __shared__ char lds[5 * 8192];          // 2 A stages + 3 B stages
  char* As = lds;
  char* Bs = lds + 2 * 8192;

  int bid = blockIdx.x;
  bool isVal = bid < NVBLK;
  int vbid = isVal ? bid : bid - NVBLK;
  int ntiles = isVal ? 2 : 3;
  int N      = isVal ? 256 : 384;
  const float* Av = isVal ? Aval : Aoff;
  const unsigned short* WS = isVal ? WvS : WcS;
  const float* bias = isVal ? bv : bcat;

  int tid = threadIdx.x, wave = tid >> 6, lane = tid & 63;
  int mt = vbid / ntiles, nt = vbid - mt * ntiles;
  int r16 = lane & 15, kg = lane >> 4;
  int wm = wave >> 1, wn = wave & 1;
  int arow = tid >> 1, ahalf = tid & 1;

  const unsigned short* Bpanel = WS + (size_t)nt * (NT * 512 * 8);
  const float* Ag32 = Av + (size_t)(mt * 128 + arow) * K + ahalf * 16;

  f32x4 ar[2][4];
  f32x4 acc[4][4] = {};

  auto stageB = [&](int s) {
    char* Bd = Bs + (s % 3) * 8192;
    const unsigned short* sp = Bpanel + (size_t)s * 512 * 8;
#pragma unroll
    for (int j = 0; j < 2; j++) {
      int f = (j * 4 + wave) * 64 + lane;
      gload16(sp + f * 8, Bd + f * 16);
    }
  };
  auto loadA32 = [&](int s, f32x4* r) {
    const float* sp = Ag32 + s * 32;
    r[0] = *(const f32x4*)(sp);
    r[1] = *(const f32x4*)(sp + 4);
    r[2] = *(const f32x4*)(sp + 8);
    r[3] = *(const f32x4*)(sp + 12);
  };
  auto writeA32 = [&](int slot, f32x4* r) {
    bf16x8 g0, g1;
    g0[0]=(__bf16)r[0][0]; g0[1]=(__bf16)r[0][1]; g0[2]=(__bf16)r[0][2]; g0[3]=(__bf16)r[0][3];
    g0[4]=(__bf16)r[1][0]; g0[5]=(__bf16)r[1][1]; g0[6]=(__bf16)r[1][2]; g0[7]=(__bf16)r[1][3];
    g1[0]=(__bf16)r[2][0]; g1[1]=(__bf16)r[2][1]; g1[2]=(__bf16)r[2][2]; g1[3]=(__bf16)r[2][3];
    g1[4]=(__bf16)r[3][0]; g1[5]=(__bf16)r[3][1]; g1[6]=(__bf16)r[3][2]; g1[7]=(__bf16)r[3][3];
    char* Ad = As + slot * 8192;
    int u0 = ahalf * 2;
    *(bf16x8*)(Ad + (((u0    ) * 128 + arow) << 4)) = g0;
    *(bf16x8*)(Ad + (((u0 + 1) * 128 + arow) << 4)) = g1;
  };
  auto compute = [&](int sa, int sb) {
    const char* Ad = As + sa * 8192;
    const char* Bd = Bs + sb * 8192;
    bf16x8 af[4], bq[4];
#pragma unroll
    for (int mi = 0; mi < 4; mi++) {
      int row = wm * 64 + mi * 16 + r16;
      af[mi] = *(const bf16x8*)(Ad + ((kg * 128 + row) << 4));
    }
#pragma unroll
    for (int ni = 0; ni < 4; ni++) {
      int row = wn * 64 + ni * 16 + r16;
      bq[ni] = *(const bf16x8*)(Bd + ((kg * 128 + row) << 4));
    }
#pragma unroll
    for (int mi = 0; mi < 4; mi++)
#pragma unroll
      for (int ni = 0; ni < 4; ni++)
        acc[mi][ni] = __builtin_amdgcn_mfma_f32_16x16x32_bf16(af[mi], bq[ni], acc[mi][ni], 0, 0, 0);
  };

  loadA32(0, ar[0]); stageB(0); loadA32(1, ar[1]); stageB(1);
  asm volatile("s_waitcnt vmcnt(%0)" :: "i"(STEADY) : "memory");
  writeA32(0, ar[0]);
  pipe_barrier();

  auto step = [&](auto TC) {
    constexpr int t = decltype(TC)::v;
    if constexpr (t + 2 < NT) {
      loadA32(t + 2, ar[(t + 2) & 1]);
      stageB(t + 2);
    }
    compute(t & 1, t % 3);
    if constexpr (t + 1 < NT) {
      if constexpr (t + 2 < NT)
        asm volatile("s_waitcnt vmcnt(%0)" :: "i"(STEADY) : "memory");
      else
        asm volatile("s_waitcnt vmcnt(0)" ::: "memory");
      writeA32((t + 1) & 1, ar[(t + 1) & 1]);
      pipe_barrier();
    }
  };
  step(IC<0>{}); step(IC<1>{}); step(IC<2>{}); step(IC<3>{});
  step(IC<4>{}); step(IC<5>{}); step(IC<6>{}); step(IC<7>{});

  int row0 = mt * 128 + wm * 64 + kg * 4;
  int col0 = nt * 128 + wn * 64 + r16;
#pragma unroll
  for (int ni = 0; ni < 4; ni++) {
    int col = col0 + ni * 16;
    float bs = bias[col];
#pragma unroll
    for (int mi = 0; mi < 4; mi++) {
#pragma unroll
      for (int j = 0; j < 4; j++) {
        int row = row0 + mi * 16 + j;
        float v = acc[mi][ni][j] + bs;
        if (isVal) Cval[(size_t)row * 256 + col] = f2bf(v);
        else       Coff[(size_t)row * 384 + col] = v;
      }
    }
  }
}

// ---------------- final GEMM (gemm3, bf16 staged A): out = interS @ WoS + bout --
__global__ __launch_bounds__(256) void gemm3b_k(const unsigned short* __restrict__ Av,
                                                const unsigned short* __restrict__ WS,
                                                const float* __restrict__ bias,
                                                float* __restrict__ C, int M, int N) {
  constexpr int NT = 8;
  constexpr int STEADY = 4;
  __shared__ char lds[6 * 8192];
  char* As = lds;
  char* Bs = lds + 3 * 8192;

  int tid = threadIdx.x, wave = tid >> 6, lane = tid & 63;
  int ntiles = N >> 7;
  int mt = blockIdx.x / ntiles, nt = blockIdx.x - (blockIdx.x / ntiles) * ntiles;
  int r16 = lane & 15, kg = lane >> 4;
  int wm = wave >> 1, wn = wave & 1;

  const unsigned short* Bpanel = WS + (size_t)nt * (NT * 512 * 8);
  const unsigned short* Apanel = Av + (size_t)mt * (NT * 512 * 8);

  f32x4 acc[4][4] = {};

  auto stageB = [&](int s) {
    char* Bd = Bs + (s % 3) * 8192;
    const unsigned short* sp = Bpanel + (size_t)s * 512 * 8;
#pragma unroll
    for (int j = 0; j < 2; j++) {
      int f = (j * 4 + wave) * 64 + lane;
      gload16(sp + f * 8, Bd + f * 16);
    }
  };
  auto stageA16 = [&](int s) {
    char* Ad = As + (s % 3) * 8192;
    const unsigned short* sp = Apanel + (size_t)s * 512 * 8;
#pragma unroll
    for (int j = 0; j < 2; j++) {
      int f = (j * 4 + wave) * 64 + lane;
      gload16(sp + f * 8, Ad + f * 16);
    }
  };
  auto compute = [&](int s) {
    const char* Ad = As + (s % 3) * 8192;
    const char* Bd = Bs + (s % 3) * 8192;
    bf16x8 af[4], bq[4];
#pragma unroll
    for (int mi = 0; mi < 4; mi++) {
      int row = wm * 64 + mi * 16 + r16;
      af[mi] = *(const bf16x8*)(Ad + ((kg * 128 + row) << 4));
    }
#pragma unroll
    for (int ni = 0; ni < 4; ni++) {
      int row = wn * 64 + ni * 16 + r16;
      bq[ni] = *(const bf16x8*)(Bd + ((kg * 128 + row) << 4));
    }
#pragma unroll
    for (int mi = 0; mi < 4; mi++)
#pragma unroll
      for (int ni = 0; ni < 4; ni++)
        acc[mi][ni] = __builtin_amdgcn_mfma_f32_16x16x32_bf16(af[mi], bq[ni], acc[mi][ni], 0, 0, 0);
  };

  stageA16(0); stageB(0); stageA16(1); stageB(1);
  asm volatile("s_waitcnt vmcnt(%0)" :: "i"(STEADY) : "memory");
  pipe_barrier();

  auto step = [&](auto TC) {
    constexpr int t = decltype(TC)::v;
    if constexpr (t + 2 < NT) { stageA16(t + 2); stageB(t + 2); }
    compute(t);
    if constexpr (t + 1 < NT) {
      if constexpr (t + 2 < NT)
        asm volatile("s_waitcnt vmcnt(%0)" :: "i"(STEADY) : "memory");
      else
        asm volatile("s_waitcnt vmcnt(0)" ::: "memory");
      pipe_barrier();
    }
  };
  step(IC<0>{}); step(IC<1>{}); step(IC<2>{}); step(IC<3>{});
  step(IC<4>{}); step(IC<5>{}); step(IC<6>{}); step(IC<7>{});

  int row0 = mt * 128 + wm * 64 + kg * 4;
  int col0 = nt * 128 + wn * 64 + r16;
#pragma unroll
  for (int ni = 0; ni < 4; ni++) {
    int col = col0 + ni * 16;
    float bs = bias[col];
#pragma unroll
    for (int mi = 0; mi < 4; mi++) {
#pragma unroll
      for (int j = 0; j < 4; j++) {
        int row = row0 + mi * 16 + j;
        C[(size_t)row * N + col] = acc[mi][ni][j] + bs;
      }
    }
  }
}

// ---------------- sampling (R6 verbatim): batched 16-gather MLP, staged store --
__global__ __launch_bounds__(256, 3) void sample_k(const float* __restrict__ offattn, // [MQ,384]
                                                   const float* __restrict__ refp,    // [B,Q,4,2]
                                                   const unsigned short* __restrict__ value,
                                                   unsigned short* __restrict__ interS) {
  int t  = blockIdx.x * 256 + threadIdx.x;
  int bq = t >> 5;
  int h  = (t >> 2) & 7;
  int c0 = (t & 3) << 3;
  int b  = bq / QQ;

  const float* base = offattn + (size_t)bq * 384;

  float lg[16];
  const float4* ab4 = (const float4*)(base + 256 + h * 16);
#pragma unroll
  for (int i = 0; i < 4; i++) {
    float4 v = ab4[i];
    lg[4*i] = v.x; lg[4*i+1] = v.y; lg[4*i+2] = v.z; lg[4*i+3] = v.w;
  }
  float m = -1e30f;
#pragma unroll
  for (int i = 0; i < 16; i++) m = fmaxf(m, lg[i]);
  float s = 0.f;
#pragma unroll
  for (int i = 0; i < 16; i++) { lg[i] = __expf(lg[i] - m); s += lg[i]; }
  float inv = 1.0f / s;

  float4 r01 = ((const float4*)(refp + (size_t)bq * 8))[0];
  float4 r23 = ((const float4*)(refp + (size_t)bq * 8))[1];
  float rxs[4] = {r01.x, r01.z, r23.x, r23.z};
  float rys[4] = {r01.y, r01.w, r23.y, r23.w};

  const unsigned short* vb = value + (size_t)b * (LTOTAL * 256) + h * 32 + c0;
  const int startL[4] = {0, 4096, 5120, 5376};

  float acc[8] = {};
#pragma unroll
  for (int lvl = 0; lvl < 4; lvl++) {
    int   Wi = 64 >> lvl;
    float Wf = (float)Wi;
    float px = rxs[lvl] * Wf - 0.5f;
    float py = rys[lvl] * Wf - 0.5f;
    const unsigned short* vl = vb + (size_t)startL[lvl] * 256;

    const float4* ob4 = (const float4*)(base + h * 32 + lvl * 8);
    float4 o01 = ob4[0], o23 = ob4[1];
    float oxs[4] = {o01.x, o01.z, o23.x, o23.z};
    float oys[4] = {o01.y, o01.w, o23.y, o23.w};

    float cw[16];
    int   coff[16];
#pragma unroll
    for (int pt = 0; pt < 4; pt++) {
      float wa = lg[lvl * 4 + pt] * inv;
      float x = px + oxs[pt];
      float y = py + oys[pt];
      float xf = floorf(x), yf = floorf(y);
      float lx = x - xf, ly = y - yf;
      int x0 = (int)xf, y0 = (int)yf;
      float wx[2] = {1.f - lx, lx};
      float wy[2] = {1.f - ly, ly};
#pragma unroll
      for (int cy = 0; cy < 2; cy++) {
        int Y = y0 + cy;
        bool vy = (unsigned)Y < (unsigned)Wi;
        int Yc = min(max(Y, 0), Wi - 1);
#pragma unroll
        for (int cx = 0; cx < 2; cx++) {
          int X = x0 + cx;
          bool vx = (unsigned)X < (unsigned)Wi;
          int Xc = min(max(X, 0), Wi - 1);
          int c = pt * 4 + cy * 2 + cx;
          cw[c]   = (vx && vy) ? wa * wy[cy] * wx[cx] : 0.f;
          coff[c] = (Yc * Wi + Xc) * 256;
        }
      }
    }
    uint4 raw[16];
#pragma unroll
    for (int c = 0; c < 16; c++) raw[c] = *(const uint4*)(vl + coff[c]);
#pragma unroll
    for (int c = 0; c < 16; c++) {
      float w = cw[c];
      acc[0] += w * b2f_lo(raw[c].x); acc[1] += w * b2f_hi(raw[c].x);
      acc[2] += w * b2f_lo(raw[c].y); acc[3] += w * b2f_hi(raw[c].y);
      acc[4] += w * b2f_lo(raw[c].z); acc[5] += w * b2f_hi(raw[c].z);
      acc[6] += w * b2f_lo(raw[c].w); acc[7] += w * b2f_hi(raw[c].w);
    }
  }

  unsigned o0 = f2bf(acc[0]) | ((unsigned)f2bf(acc[1]) << 16);
  unsigned o1 = f2bf(acc[2]) | ((unsigned)f2bf(acc[3]) << 16);
  unsigned o2 = f2bf(acc[4]) | ((unsigned)f2bf(acc[5]) << 16);
  unsigned o3 = f2bf(acc[6]) | ((unsigned)f2bf(acc[7]) << 16);
  uint4 st = {o0, o1, o2, o3};

  // staged layout: tile = bq>>7, row = bq&127, stage = h, u = c0>>3
  int mtile = bq >> 7, row = bq & 127;
  size_t goff = (((size_t)(mtile * 8 + h)) * 512 + (c0 >> 3) * 128 + row) * 8;
  *(uint4*)(interS + goff) = st;
}

extern "C" void kernel_launch(void* const* d_in, const int* in_sizes, int n_in,
                              void* d_out, int out_size, void* d_ws, size_t ws_size,
                              hipStream_t stream) {
  const float* query  = (const float*)d_in[0];
  const float* refp   = (const float*)d_in[1];
  const float* inputf = (const float*)d_in[2];
  const float* Wv   = (const float*)d_in[5];
  const float* bv   = (const float*)d_in[6];
  const float* Wo   = (const float*)d_in[7];
  const float* bo   = (const float*)d_in[8];
  const float* Wa   = (const float*)d_in[9];
  const float* ba   = (const float*)d_in[10];
  const float* Wout = (const float*)d_in[11];
  const float* bout = (const float*)d_in[12];

  char* p = (char*)d_ws;
  auto alloc = [&](size_t bytes) -> char* {
    char* r = p;
    p += (bytes + 255) & ~(size_t)255;
    return r;
  };
  unsigned short* val   = (unsigned short*)alloc((size_t)MV * 256 * 2);
  unsigned short* WvS   = (unsigned short*)alloc(2 * 4096 * 8 * 2);
  unsigned short* WcS   = (unsigned short*)alloc(3 * 4096 * 8 * 2);
  unsigned short* WoS   = (unsigned short*)alloc(2 * 4096 * 8 * 2);
  float*          bcat  = (float*)alloc(384 * 4);
  float*          offattn = (float*)alloc((size_t)MQ * 384 * 4);
  unsigned short* interS = (unsigned short*)alloc((size_t)MQ * 256 * 2);

  prep_k<<<114, 256, 0, stream>>>(Wv, Wo, Wa, Wout, bo, ba, WvS, WcS, WoS, bcat);

  // fused: value GEMM (1360 blocks) + offattn GEMM (375 blocks), one dispatch
  gemmf_k<<<NVBLK + NOBLK, 256, 0, stream>>>(inputf, query, WvS, WcS, bv, bcat,
                                             val, offattn);
  // sampling -> interS (staged bf16)
  sample_k<<<MQ * 32 / 256, 256, 0, stream>>>(offattn, refp, val, interS);
  // out = interS @ Wout + bout -> fp32 d_out
  gemm3b_k<<<(MQ / 128) * 2, 256, 0, stream>>>(interS, WoS, bout, (float*)d_out,
                                               MQ, 256);
}

// Round 10
// 101.228 us; speedup vs baseline: 1.4010x; 1.1443x over previous
//
#include <hip/hip_runtime.h>

#define BB 16
#define QQ 1000
#define NH 8
#define LTOTAL 5440
#define MQ (BB*QQ)      // 16000
#define MV (BB*LTOTAL)  // 87040
#define NVBLK ((MV/128)*2)   // 1360 value-GEMM blocks
#define NOBLK ((MQ/128)*3)   // 375 offattn-GEMM blocks

typedef __bf16 bf16x8 __attribute__((ext_vector_type(8)));
typedef float  f32x4  __attribute__((ext_vector_type(4)));

template <int N> struct IC { static constexpr int v = N; };

__device__ __forceinline__ unsigned short f2bf(float f) {
  unsigned u = __builtin_bit_cast(unsigned, f);
  u += 0x7fffu + ((u >> 16) & 1u);
  return (unsigned short)(u >> 16);
}
__device__ __forceinline__ float b2f_lo(unsigned u) {
  return __builtin_bit_cast(float, u << 16);
}
__device__ __forceinline__ float b2f_hi(unsigned u) {
  return __builtin_bit_cast(float, u & 0xffff0000u);
}

__device__ __forceinline__ void gload16(const void* g, void* l) {
  __builtin_amdgcn_global_load_lds(
      (const __attribute__((address_space(1))) unsigned int*)g,
      (__attribute__((address_space(3))) unsigned int*)l, 16, 0, 0);
}

// lgkmcnt(0) + raw barrier; vmcnt deliberately NOT drained.
__device__ __forceinline__ void pipe_barrier() {
  asm volatile("s_waitcnt lgkmcnt(0)" ::: "memory");
  __builtin_amdgcn_sched_barrier(0);
  __builtin_amdgcn_s_barrier();
  __builtin_amdgcn_sched_barrier(0);
}

// ---------------- prep: weights -> [panel][k_octet][n] granule layout + biases --
__global__ __launch_bounds__(256) void prep_k(const float* __restrict__ Wv,
                                              const float* __restrict__ Wo,
                                              const float* __restrict__ Wa,
                                              const float* __restrict__ Wout,
                                              const float* __restrict__ bo,
                                              const float* __restrict__ ba,
                                              unsigned short* __restrict__ WvS,  // 2 panels
                                              unsigned short* __restrict__ WcS,  // 3 panels
                                              unsigned short* __restrict__ WoS,  // 2 panels
                                              float* __restrict__ bcat) {
  int i = blockIdx.x * 256 + threadIdx.x;
  if (i < 28672) {
    const float* src;
    unsigned short* dst;
    int g, srcN;
    if (i < 8192)       { g = i;         dst = WvS; src = Wv;   srcN = 256; }
    else if (i < 20480) { g = i - 8192;  dst = WcS; src = Wo;   srcN = 256; }
    else                { g = i - 20480; dst = WoS; src = Wout; srcN = 256; }
    int panel = g >> 12, ko = (g >> 7) & 31, row = g & 127;
    int kbase = ko * 8;
    int n = panel * 128 + row;
    if (dst == WcS && panel == 2) { src = Wa; srcN = 128; n = row; }
    bf16x8 r;
#pragma unroll
    for (int e = 0; e < 8; e++) r[e] = (__bf16)src[(size_t)(kbase + e) * srcN + n];
    *(bf16x8*)(dst + (size_t)g * 8) = r;
  } else if (i < 29056) {
    int j = i - 28672;
    bcat[j] = j < 256 ? bo[j] : ba[j - 256];
  }
}

// ---------------- fused value+offattn GEMM, one dispatch -----------------------
// bid < NVBLK : value = input_flatten @ WvS + bv -> bf16 [MV,256]
// else        : offattn = query @ WcS + bcat     -> fp32 [MQ,384]
// Schedule = gemm3 (R6). NEW vs R9: (1) bijective XCD swizzle (m204) so blocks
// sharing A-row panels land on one XCD's L2; (2) swapped-operand MFMA ->
// thread owns 1 row x 4 consecutive cols -> uint2/f32x4 epilogue stores
// (kills the 98-vs-69MB write amplification seen in R9).
__global__ __launch_bounds__(256) void gemmf_k(const float* __restrict__ Aval,
                                               const float* __restrict__ Aoff,
                                               const unsigned short* __restrict__ WvS,
                                               const unsigned short* __restrict__ WcS,
                                               const float* __restrict__ bv,
                                               const float* __restrict__ bcat,
                                               unsigned short* __restrict__ Cval,
                                               float* __restrict__ Coff) {
  constexpr int K = 256, NT = 8;
  constexpr int STEADY = 6;
  constexpr int NWG = NVBLK + NOBLK;           // 1735
  constexpr int QC = NWG / 8, RC = NWG % 8;    // 216, 7
  __shared__ char lds[5 * 8192];               // 2 A stages + 3 B stages
  char* As = lds;
  char* Bs = lds + 2 * 8192;

  int orig = blockIdx.x;
  int xcd = orig & 7, pos = orig >> 3;
  int bid = (xcd < RC ? xcd * (QC + 1) : RC * (QC + 1) + (xcd - RC) * QC) + pos;

  bool isVal = bid < NVBLK;
  int vbid = isVal ? bid : bid - NVBLK;
  int ntiles = isVal ? 2 : 3;
  const float* Av = isVal ? Aval : Aoff;
  const unsigned short* WS = isVal ? WvS : WcS;
  const float* bias = isVal ? bv : bcat;

  int tid = threadIdx.x, wave = tid >> 6, lane = tid & 63;
  int mt = vbid / ntiles, nt = vbid - mt * ntiles;
  int r16 = lane & 15, kg = lane >> 4;
  int wm = wave >> 1, wn = wave & 1;
  int arow = tid >> 1, ahalf = tid & 1;

  const unsigned short* Bpanel = WS + (size_t)nt * (NT * 512 * 8);
  const float* Ag32 = Av + (size_t)(mt * 128 + arow) * K + ahalf * 16;

  f32x4 ar[2][4];
  f32x4 acc[4][4] = {};

  auto stageB = [&](int s) {
    char* Bd = Bs + (s % 3) * 8192;
    const unsigned short* sp = Bpanel + (size_t)s * 512 * 8;
#pragma unroll
    for (int j = 0; j < 2; j++) {
      int f = (j * 4 + wave) * 64 + lane;
      gload16(sp + f * 8, Bd + f * 16);
    }
  };
  auto loadA32 = [&](int s, f32x4* r) {
    const float* sp = Ag32 + s * 32;
    r[0] = *(const f32x4*)(sp);
    r[1] = *(const f32x4*)(sp + 4);
    r[2] = *(const f32x4*)(sp + 8);
    r[3] = *(const f32x4*)(sp + 12);
  };
  auto writeA32 = [&](int slot, f32x4* r) {
    bf16x8 g0, g1;
    g0[0]=(__bf16)r[0][0]; g0[1]=(__bf16)r[0][1]; g0[2]=(__bf16)r[0][2]; g0[3]=(__bf16)r[0][3];
    g0[4]=(__bf16)r[1][0]; g0[5]=(__bf16)r[1][1]; g0[6]=(__bf16)r[1][2]; g0[7]=(__bf16)r[1][3];
    g1[0]=(__bf16)r[2][0]; g1[1]=(__bf16)r[2][1]; g1[2]=(__bf16)r[2][2]; g1[3]=(__bf16)r[2][3];
    g1[4]=(__bf16)r[3][0]; g1[5]=(__bf16)r[3][1]; g1[6]=(__bf16)r[3][2]; g1[7]=(__bf16)r[3][3];
    char* Ad = As + slot * 8192;
    int u0 = ahalf * 2;
    *(bf16x8*)(Ad + (((u0    ) * 128 + arow) << 4)) = g0;
    *(bf16x8*)(Ad + (((u0 + 1) * 128 + arow) << 4)) = g1;
  };
  auto compute = [&](int sa, int sb) {
    const char* Ad = As + sa * 8192;
    const char* Bd = Bs + sb * 8192;
    bf16x8 af[4], bq[4];
#pragma unroll
    for (int mi = 0; mi < 4; mi++) {
      int row = wm * 64 + mi * 16 + r16;
      af[mi] = *(const bf16x8*)(Ad + ((kg * 128 + row) << 4));
    }
#pragma unroll
    for (int ni = 0; ni < 4; ni++) {
      int row = wn * 64 + ni * 16 + r16;
      bq[ni] = *(const bf16x8*)(Bd + ((kg * 128 + row) << 4));
    }
    // swapped operands: D rows = B's n-dim, D cols = A's m-dim
#pragma unroll
    for (int mi = 0; mi < 4; mi++)
#pragma unroll
      for (int ni = 0; ni < 4; ni++)
        acc[mi][ni] = __builtin_amdgcn_mfma_f32_16x16x32_bf16(bq[ni], af[mi], acc[mi][ni], 0, 0, 0);
  };

  loadA32(0, ar[0]); stageB(0); loadA32(1, ar[1]); stageB(1);
  asm volatile("s_waitcnt vmcnt(%0)" :: "i"(STEADY) : "memory");
  writeA32(0, ar[0]);
  pipe_barrier();

  auto step = [&](auto TC) {
    constexpr int t = decltype(TC)::v;
    if constexpr (t + 2 < NT) {
      loadA32(t + 2, ar[(t + 2) & 1]);
      stageB(t + 2);
    }
    compute(t & 1, t % 3);
    if constexpr (t + 1 < NT) {
      if constexpr (t + 2 < NT)
        asm volatile("s_waitcnt vmcnt(%0)" :: "i"(STEADY) : "memory");
      else
        asm volatile("s_waitcnt vmcnt(0)" ::: "memory");
      writeA32((t + 1) & 1, ar[(t + 1) & 1]);
      pipe_barrier();
    }
  };
  step(IC<0>{}); step(IC<1>{}); step(IC<2>{}); step(IC<3>{});
  step(IC<4>{}); step(IC<5>{}); step(IC<6>{}); step(IC<7>{});

  // vectorized epilogue: row = base + mi*16 + r16; cols = base + ni*16 + kg*4 +{0..3}
  int rowBase = mt * 128 + wm * 64;
  int colBase = nt * 128 + wn * 64;
#pragma unroll
  for (int ni = 0; ni < 4; ni++) {
    int col = colBase + ni * 16 + kg * 4;
    f32x4 bs = *(const f32x4*)(bias + col);
#pragma unroll
    for (int mi = 0; mi < 4; mi++) {
      int row = rowBase + mi * 16 + r16;
      f32x4 v = acc[mi][ni] + bs;
      if (isVal) {
        uint2 st;
        st.x = f2bf(v[0]) | ((unsigned)f2bf(v[1]) << 16);
        st.y = f2bf(v[2]) | ((unsigned)f2bf(v[3]) << 16);
        *(uint2*)(Cval + (size_t)row * 256 + col) = st;
      } else {
        *(f32x4*)(Coff + (size_t)row * 384 + col) = v;
      }
    }
  }
}

// ---------------- final GEMM (gemm3, bf16 staged A): out = interS @ WoS + bout --
__global__ __launch_bounds__(256) void gemm3b_k(const unsigned short* __restrict__ Av,
                                                const unsigned short* __restrict__ WS,
                                                const float* __restrict__ bias,
                                                float* __restrict__ C, int M, int N) {
  constexpr int NT = 8;
  constexpr int STEADY = 4;
  __shared__ char lds[6 * 8192];
  char* As = lds;
  char* Bs = lds + 3 * 8192;

  int tid = threadIdx.x, wave = tid >> 6, lane = tid & 63;
  int ntiles = N >> 7;
  int mt = blockIdx.x / ntiles, nt = blockIdx.x - (blockIdx.x / ntiles) * ntiles;
  int r16 = lane & 15, kg = lane >> 4;
  int wm = wave >> 1, wn = wave & 1;

  const unsigned short* Bpanel = WS + (size_t)nt * (NT * 512 * 8);
  const unsigned short* Apanel = Av + (size_t)mt * (NT * 512 * 8);

  f32x4 acc[4][4] = {};

  auto stageB = [&](int s) {
    char* Bd = Bs + (s % 3) * 8192;
    const unsigned short* sp = Bpanel + (size_t)s * 512 * 8;
#pragma unroll
    for (int j = 0; j < 2; j++) {
      int f = (j * 4 + wave) * 64 + lane;
      gload16(sp + f * 8, Bd + f * 16);
    }
  };
  auto stageA16 = [&](int s) {
    char* Ad = As + (s % 3) * 8192;
    const unsigned short* sp = Apanel + (size_t)s * 512 * 8;
#pragma unroll
    for (int j = 0; j < 2; j++) {
      int f = (j * 4 + wave) * 64 + lane;
      gload16(sp + f * 8, Ad + f * 16);
    }
  };
  auto compute = [&](int s) {
    const char* Ad = As + (s % 3) * 8192;
    const char* Bd = Bs + (s % 3) * 8192;
    bf16x8 af[4], bq[4];
#pragma unroll
    for (int mi = 0; mi < 4; mi++) {
      int row = wm * 64 + mi * 16 + r16;
      af[mi] = *(const bf16x8*)(Ad + ((kg * 128 + row) << 4));
    }
#pragma unroll
    for (int ni = 0; ni < 4; ni++) {
      int row = wn * 64 + ni * 16 + r16;
      bq[ni] = *(const bf16x8*)(Bd + ((kg * 128 + row) << 4));
    }
#pragma unroll
    for (int mi = 0; mi < 4; mi++)
#pragma unroll
      for (int ni = 0; ni < 4; ni++)
        acc[mi][ni] = __builtin_amdgcn_mfma_f32_16x16x32_bf16(bq[ni], af[mi], acc[mi][ni], 0, 0, 0);
  };

  stageA16(0); stageB(0); stageA16(1); stageB(1);
  asm volatile("s_waitcnt vmcnt(%0)" :: "i"(STEADY) : "memory");
  pipe_barrier();

  auto step = [&](auto TC) {
    constexpr int t = decltype(TC)::v;
    if constexpr (t + 2 < NT) { stageA16(t + 2); stageB(t + 2); }
    compute(t);
    if constexpr (t + 1 < NT) {
      if constexpr (t + 2 < NT)
        asm volatile("s_waitcnt vmcnt(%0)" :: "i"(STEADY) : "memory");
      else
        asm volatile("s_waitcnt vmcnt(0)" ::: "memory");
      pipe_barrier();
    }
  };
  step(IC<0>{}); step(IC<1>{}); step(IC<2>{}); step(IC<3>{});
  step(IC<4>{}); step(IC<5>{}); step(IC<6>{}); step(IC<7>{});

  int rowBase = mt * 128 + wm * 64;
  int colBase = nt * 128 + wn * 64;
#pragma unroll
  for (int ni = 0; ni < 4; ni++) {
    int col = colBase + ni * 16 + kg * 4;
    f32x4 bs = *(const f32x4*)(bias + col);
#pragma unroll
    for (int mi = 0; mi < 4; mi++) {
      int row = rowBase + mi * 16 + r16;
      f32x4 v = acc[mi][ni] + bs;
      *(f32x4*)(C + (size_t)row * N + col) = v;
    }
  }
}

// ---------------- sampling (R6 verbatim): batched 16-gather MLP, staged store --
__global__ __launch_bounds__(256, 3) void sample_k(const float* __restrict__ offattn, // [MQ,384]
                                                   const float* __restrict__ refp,    // [B,Q,4,2]
                                                   const unsigned short* __restrict__ value,
                                                   unsigned short* __restrict__ interS) {
  int t  = blockIdx.x * 256 + threadIdx.x;
  int bq = t >> 5;
  int h  = (t >> 2) & 7;
  int c0 = (t & 3) << 3;
  int b  = bq / QQ;

  const float* base = offattn + (size_t)bq * 384;

  float lg[16];
  const float4* ab4 = (const float4*)(base + 256 + h * 16);
#pragma unroll
  for (int i = 0; i < 4; i++) {
    float4 v = ab4[i];
    lg[4*i] = v.x; lg[4*i+1] = v.y; lg[4*i+2] = v.z; lg[4*i+3] = v.w;
  }
  float m = -1e30f;
#pragma unroll
  for (int i = 0; i < 16; i++) m = fmaxf(m, lg[i]);
  float s = 0.f;
#pragma unroll
  for (int i = 0; i < 16; i++) { lg[i] = __expf(lg[i] - m); s += lg[i]; }
  float inv = 1.0f / s;

  float4 r01 = ((const float4*)(refp + (size_t)bq * 8))[0];
  float4 r23 = ((const float4*)(refp + (size_t)bq * 8))[1];
  float rxs[4] = {r01.x, r01.z, r23.x, r23.z};
  float rys[4] = {r01.y, r01.w, r23.y, r23.w};

  const unsigned short* vb = value + (size_t)b * (LTOTAL * 256) + h * 32 + c0;
  const int startL[4] = {0, 4096, 5120, 5376};

  float acc[8] = {};
#pragma unroll
  for (int lvl = 0; lvl < 4; lvl++) {
    int   Wi = 64 >> lvl;
    float Wf = (float)Wi;
    float px = rxs[lvl] * Wf - 0.5f;
    float py = rys[lvl] * Wf - 0.5f;
    const unsigned short* vl = vb + (size_t)startL[lvl] * 256;

    const float4* ob4 = (const float4*)(base + h * 32 + lvl * 8);
    float4 o01 = ob4[0], o23 = ob4[1];
    float oxs[4] = {o01.x, o01.z, o23.x, o23.z};
    float oys[4] = {o01.y, o01.w, o23.y, o23.w};

    float cw[16];
    int   coff[16];
#pragma unroll
    for (int pt = 0; pt < 4; pt++) {
      float wa = lg[lvl * 4 + pt] * inv;
      float x = px + oxs[pt];
      float y = py + oys[pt];
      float xf = floorf(x), yf = floorf(y);
      float lx = x - xf, ly = y - yf;
      int x0 = (int)xf, y0 = (int)yf;
      float wx[2] = {1.f - lx, lx};
      float wy[2] = {1.f - ly, ly};
#pragma unroll
      for (int cy = 0; cy < 2; cy++) {
        int Y = y0 + cy;
        bool vy = (unsigned)Y < (unsigned)Wi;
        int Yc = min(max(Y, 0), Wi - 1);
#pragma unroll
        for (int cx = 0; cx < 2; cx++) {
          int X = x0 + cx;
          bool vx = (unsigned)X < (unsigned)Wi;
          int Xc = min(max(X, 0), Wi - 1);
          int c = pt * 4 + cy * 2 + cx;
          cw[c]   = (vx && vy) ? wa * wy[cy] * wx[cx] : 0.f;
          coff[c] = (Yc * Wi + Xc) * 256;
        }
      }
    }
    uint4 raw[16];
#pragma unroll
    for (int c = 0; c < 16; c++) raw[c] = *(const uint4*)(vl + coff[c]);
#pragma unroll
    for (int c = 0; c < 16; c++) {
      float w = cw[c];
      acc[0] += w * b2f_lo(raw[c].x); acc[1] += w * b2f_hi(raw[c].x);
      acc[2] += w * b2f_lo(raw[c].y); acc[3] += w * b2f_hi(raw[c].y);
      acc[4] += w * b2f_lo(raw[c].z); acc[5] += w * b2f_hi(raw[c].z);
      acc[6] += w * b2f_lo(raw[c].w); acc[7] += w * b2f_hi(raw[c].w);
    }
  }

  unsigned o0 = f2bf(acc[0]) | ((unsigned)f2bf(acc[1]) << 16);
  unsigned o1 = f2bf(acc[2]) | ((unsigned)f2bf(acc[3]) << 16);
  unsigned o2 = f2bf(acc[4]) | ((unsigned)f2bf(acc[5]) << 16);
  unsigned o3 = f2bf(acc[6]) | ((unsigned)f2bf(acc[7]) << 16);
  uint4 st = {o0, o1, o2, o3};

  // staged layout: tile = bq>>7, row = bq&127, stage = h, u = c0>>3
  int mtile = bq >> 7, row = bq & 127;
  size_t goff = (((size_t)(mtile * 8 + h)) * 512 + (c0 >> 3) * 128 + row) * 8;
  *(uint4*)(interS + goff) = st;
}

extern "C" void kernel_launch(void* const* d_in, const int* in_sizes, int n_in,
                              void* d_out, int out_size, void* d_ws, size_t ws_size,
                              hipStream_t stream) {
  const float* query  = (const float*)d_in[0];
  const float* refp   = (const float*)d_in[1];
  const float* inputf = (const float*)d_in[2];
  const float* Wv   = (const float*)d_in[5];
  const float* bv   = (const float*)d_in[6];
  const float* Wo   = (const float*)d_in[7];
  const float* bo   = (const float*)d_in[8];
  const float* Wa   = (const float*)d_in[9];
  const float* ba   = (const float*)d_in[10];
  const float* Wout = (const float*)d_in[11];
  const float* bout = (const float*)d_in[12];

  char* p = (char*)d_ws;
  auto alloc = [&](size_t bytes) -> char* {
    char* r = p;
    p += (bytes + 255) & ~(size_t)255;
    return r;
  };
  unsigned short* val   = (unsigned short*)alloc((size_t)MV * 256 * 2);
  unsigned short* WvS   = (unsigned short*)alloc(2 * 4096 * 8 * 2);
  unsigned short* WcS   = (unsigned short*)alloc(3 * 4096 * 8 * 2);
  unsigned short* WoS   = (unsigned short*)alloc(2 * 4096 * 8 * 2);
  float*          bcat  = (float*)alloc(384 * 4);
  float*          offattn = (float*)alloc((size_t)MQ * 384 * 4);
  unsigned short* interS = (unsigned short*)alloc((size_t)MQ * 256 * 2);

  prep_k<<<114, 256, 0, stream>>>(Wv, Wo, Wa, Wout, bo, ba, WvS, WcS, WoS, bcat);

  // fused: value GEMM (1360 blocks) + offattn GEMM (375 blocks), one dispatch
  gemmf_k<<<NVBLK + NOBLK, 256, 0, stream>>>(inputf, query, WvS, WcS, bv, bcat,
                                             val, offattn);
  // sampling -> interS (staged bf16)
  sample_k<<<MQ * 32 / 256, 256, 0, stream>>>(offattn, refp, val, interS);
  // out = interS @ Wout + bout -> fp32 d_out
  gemm3b_k<<<(MQ / 128) * 2, 256, 0, stream>>>(interS, WoS, bout, (float*)d_out,
                                               MQ, 256);
}

// Round 11
// 89.271 us; speedup vs baseline: 1.5886x; 1.1339x over previous
//
#include <hip/hip_runtime.h>

#define BB 16
#define QQ 1000
#define NH 8
#define LTOTAL 5440
#define MQ (BB*QQ)      // 16000
#define MV (BB*LTOTAL)  // 87040
#define NVBLK ((MV/128)*2)   // 1360 value-GEMM blocks
#define NOBLK ((MQ/128)*3)   // 375 offattn-GEMM blocks

typedef __bf16 bf16x8 __attribute__((ext_vector_type(8)));
typedef float  f32x4  __attribute__((ext_vector_type(4)));

template <int N> struct IC { static constexpr int v = N; };

__device__ __forceinline__ unsigned short f2bf(float f) {
  unsigned u = __builtin_bit_cast(unsigned, f);
  u += 0x7fffu + ((u >> 16) & 1u);
  return (unsigned short)(u >> 16);
}
__device__ __forceinline__ float b2f_lo(unsigned u) {
  return __builtin_bit_cast(float, u << 16);
}
__device__ __forceinline__ float b2f_hi(unsigned u) {
  return __builtin_bit_cast(float, u & 0xffff0000u);
}

__device__ __forceinline__ void gload16(const void* g, void* l) {
  __builtin_amdgcn_global_load_lds(
      (const __attribute__((address_space(1))) unsigned int*)g,
      (__attribute__((address_space(3))) unsigned int*)l, 16, 0, 0);
}

// lgkmcnt(0) + raw barrier; vmcnt deliberately NOT drained.
__device__ __forceinline__ void pipe_barrier() {
  asm volatile("s_waitcnt lgkmcnt(0)" ::: "memory");
  __builtin_amdgcn_sched_barrier(0);
  __builtin_amdgcn_s_barrier();
  __builtin_amdgcn_sched_barrier(0);
}

// ---------------- prep: weights -> [panel][k_octet][n] granule layout + biases --
__global__ __launch_bounds__(256) void prep_k(const float* __restrict__ Wv,
                                              const float* __restrict__ Wo,
                                              const float* __restrict__ Wa,
                                              const float* __restrict__ Wout,
                                              const float* __restrict__ bo,
                                              const float* __restrict__ ba,
                                              unsigned short* __restrict__ WvS,  // 2 panels
                                              unsigned short* __restrict__ WcS,  // 3 panels
                                              unsigned short* __restrict__ WoS,  // 2 panels
                                              float* __restrict__ bcat) {
  int i = blockIdx.x * 256 + threadIdx.x;
  if (i < 28672) {
    const float* src;
    unsigned short* dst;
    int g, srcN;
    if (i < 8192)       { g = i;         dst = WvS; src = Wv;   srcN = 256; }
    else if (i < 20480) { g = i - 8192;  dst = WcS; src = Wo;   srcN = 256; }
    else                { g = i - 20480; dst = WoS; src = Wout; srcN = 256; }
    int panel = g >> 12, ko = (g >> 7) & 31, row = g & 127;
    int kbase = ko * 8;
    int n = panel * 128 + row;
    if (dst == WcS && panel == 2) { src = Wa; srcN = 128; n = row; }
    bf16x8 r;
#pragma unroll
    for (int e = 0; e < 8; e++) r[e] = (__bf16)src[(size_t)(kbase + e) * srcN + n];
    *(bf16x8*)(dst + (size_t)g * 8) = r;
  } else if (i < 29056) {
    int j = i - 28672;
    bcat[j] = j < 256 ? bo[j] : ba[j - 256];
  }
}

// ---------------- fused value+offattn GEMM, one dispatch (R10 + writeA reorder) -
__global__ __launch_bounds__(256) void gemmf_k(const float* __restrict__ Aval,
                                               const float* __restrict__ Aoff,
                                               const unsigned short* __restrict__ WvS,
                                               const unsigned short* __restrict__ WcS,
                                               const float* __restrict__ bv,
                                               const float* __restrict__ bcat,
                                               unsigned short* __restrict__ Cval,
                                               float* __restrict__ Coff) {
  constexpr int K = 256, NT = 8;
  constexpr int STEADY = 6;
  constexpr int NWG = NVBLK + NOBLK;           // 1735
  constexpr int QC = NWG / 8, RC = NWG % 8;    // 216, 7
  __shared__ char lds[5 * 8192];               // 2 A stages + 3 B stages
  char* As = lds;
  char* Bs = lds + 2 * 8192;

  int orig = blockIdx.x;
  int xcd = orig & 7, pos = orig >> 3;
  int bid = (xcd < RC ? xcd * (QC + 1) : RC * (QC + 1) + (xcd - RC) * QC) + pos;

  bool isVal = bid < NVBLK;
  int vbid = isVal ? bid : bid - NVBLK;
  int ntiles = isVal ? 2 : 3;
  const float* Av = isVal ? Aval : Aoff;
  const unsigned short* WS = isVal ? WvS : WcS;
  const float* bias = isVal ? bv : bcat;

  int tid = threadIdx.x, wave = tid >> 6, lane = tid & 63;
  int mt = vbid / ntiles, nt = vbid - mt * ntiles;
  int r16 = lane & 15, kg = lane >> 4;
  int wm = wave >> 1, wn = wave & 1;
  int arow = tid >> 1, ahalf = tid & 1;

  const unsigned short* Bpanel = WS + (size_t)nt * (NT * 512 * 8);
  const float* Ag32 = Av + (size_t)(mt * 128 + arow) * K + ahalf * 16;

  f32x4 ar[2][4];
  f32x4 acc[4][4] = {};

  auto stageB = [&](int s) {
    char* Bd = Bs + (s % 3) * 8192;
    const unsigned short* sp = Bpanel + (size_t)s * 512 * 8;
#pragma unroll
    for (int j = 0; j < 2; j++) {
      int f = (j * 4 + wave) * 64 + lane;
      gload16(sp + f * 8, Bd + f * 16);
    }
  };
  auto loadA32 = [&](int s, f32x4* r) {
    const float* sp = Ag32 + s * 32;
    r[0] = *(const f32x4*)(sp);
    r[1] = *(const f32x4*)(sp + 4);
    r[2] = *(const f32x4*)(sp + 8);
    r[3] = *(const f32x4*)(sp + 12);
  };
  auto writeA32 = [&](int slot, f32x4* r) {
    bf16x8 g0, g1;
    g0[0]=(__bf16)r[0][0]; g0[1]=(__bf16)r[0][1]; g0[2]=(__bf16)r[0][2]; g0[3]=(__bf16)r[0][3];
    g0[4]=(__bf16)r[1][0]; g0[5]=(__bf16)r[1][1]; g0[6]=(__bf16)r[1][2]; g0[7]=(__bf16)r[1][3];
    g1[0]=(__bf16)r[2][0]; g1[1]=(__bf16)r[2][1]; g1[2]=(__bf16)r[2][2]; g1[3]=(__bf16)r[2][3];
    g1[4]=(__bf16)r[3][0]; g1[5]=(__bf16)r[3][1]; g1[6]=(__bf16)r[3][2]; g1[7]=(__bf16)r[3][3];
    char* Ad = As + slot * 8192;
    int u0 = ahalf * 2;
    *(bf16x8*)(Ad + (((u0    ) * 128 + arow) << 4)) = g0;
    *(bf16x8*)(Ad + (((u0 + 1) * 128 + arow) << 4)) = g1;
  };
  auto compute = [&](int sa, int sb) {
    const char* Ad = As + sa * 8192;
    const char* Bd = Bs + sb * 8192;
    bf16x8 af[4], bq[4];
#pragma unroll
    for (int mi = 0; mi < 4; mi++) {
      int row = wm * 64 + mi * 16 + r16;
      af[mi] = *(const bf16x8*)(Ad + ((kg * 128 + row) << 4));
    }
#pragma unroll
    for (int ni = 0; ni < 4; ni++) {
      int row = wn * 64 + ni * 16 + r16;
      bq[ni] = *(const bf16x8*)(Bd + ((kg * 128 + row) << 4));
    }
    // swapped operands: thread owns 1 row x 4 consecutive cols
#pragma unroll
    for (int mi = 0; mi < 4; mi++)
#pragma unroll
      for (int ni = 0; ni < 4; ni++)
        acc[mi][ni] = __builtin_amdgcn_mfma_f32_16x16x32_bf16(bq[ni], af[mi], acc[mi][ni], 0, 0, 0);
  };

  loadA32(0, ar[0]); stageB(0); loadA32(1, ar[1]); stageB(1);
  writeA32(0, ar[0]);
  asm volatile("s_waitcnt vmcnt(%0)" :: "i"(STEADY) : "memory");
  pipe_barrier();

  auto step = [&](auto TC) {
    constexpr int t = decltype(TC)::v;
    if constexpr (t + 2 < NT) {
      loadA32(t + 2, ar[(t + 2) & 1]);
      stageB(t + 2);
    }
    compute(t & 1, t % 3);
    if constexpr (t + 1 < NT) {
      // writeA first: its reg-waits + ds_write issue overlap the B vmcnt wait
      writeA32((t + 1) & 1, ar[(t + 1) & 1]);
      if constexpr (t + 2 < NT)
        asm volatile("s_waitcnt vmcnt(%0)" :: "i"(STEADY) : "memory");
      else
        asm volatile("s_waitcnt vmcnt(0)" ::: "memory");
      pipe_barrier();
    }
  };
  step(IC<0>{}); step(IC<1>{}); step(IC<2>{}); step(IC<3>{});
  step(IC<4>{}); step(IC<5>{}); step(IC<6>{}); step(IC<7>{});

  int rowBase = mt * 128 + wm * 64;
  int colBase = nt * 128 + wn * 64;
#pragma unroll
  for (int ni = 0; ni < 4; ni++) {
    int col = colBase + ni * 16 + kg * 4;
    f32x4 bs = *(const f32x4*)(bias + col);
#pragma unroll
    for (int mi = 0; mi < 4; mi++) {
      int row = rowBase + mi * 16 + r16;
      f32x4 v = acc[mi][ni] + bs;
      if (isVal) {
        uint2 st;
        st.x = f2bf(v[0]) | ((unsigned)f2bf(v[1]) << 16);
        st.y = f2bf(v[2]) | ((unsigned)f2bf(v[3]) << 16);
        *(uint2*)(Cval + (size_t)row * 256 + col) = st;
      } else {
        *(f32x4*)(Coff + (size_t)row * 384 + col) = v;
      }
    }
  }
}

// ---------------- final GEMM (gemm3, bf16 staged A): out = interS @ WoS + bout --
__global__ __launch_bounds__(256) void gemm3b_k(const unsigned short* __restrict__ Av,
                                                const unsigned short* __restrict__ WS,
                                                const float* __restrict__ bias,
                                                float* __restrict__ C, int M, int N) {
  constexpr int NT = 8;
  constexpr int STEADY = 4;
  __shared__ char lds[6 * 8192];
  char* As = lds;
  char* Bs = lds + 3 * 8192;

  int tid = threadIdx.x, wave = tid >> 6, lane = tid & 63;
  int ntiles = N >> 7;
  int mt = blockIdx.x / ntiles, nt = blockIdx.x - (blockIdx.x / ntiles) * ntiles;
  int r16 = lane & 15, kg = lane >> 4;
  int wm = wave >> 1, wn = wave & 1;

  const unsigned short* Bpanel = WS + (size_t)nt * (NT * 512 * 8);
  const unsigned short* Apanel = Av + (size_t)mt * (NT * 512 * 8);

  f32x4 acc[4][4] = {};

  auto stageB = [&](int s) {
    char* Bd = Bs + (s % 3) * 8192;
    const unsigned short* sp = Bpanel + (size_t)s * 512 * 8;
#pragma unroll
    for (int j = 0; j < 2; j++) {
      int f = (j * 4 + wave) * 64 + lane;
      gload16(sp + f * 8, Bd + f * 16);
    }
  };
  auto stageA16 = [&](int s) {
    char* Ad = As + (s % 3) * 8192;
    const unsigned short* sp = Apanel + (size_t)s * 512 * 8;
#pragma unroll
    for (int j = 0; j < 2; j++) {
      int f = (j * 4 + wave) * 64 + lane;
      gload16(sp + f * 8, Ad + f * 16);
    }
  };
  auto compute = [&](int s) {
    const char* Ad = As + (s % 3) * 8192;
    const char* Bd = Bs + (s % 3) * 8192;
    bf16x8 af[4], bq[4];
#pragma unroll
    for (int mi = 0; mi < 4; mi++) {
      int row = wm * 64 + mi * 16 + r16;
      af[mi] = *(const bf16x8*)(Ad + ((kg * 128 + row) << 4));
    }
#pragma unroll
    for (int ni = 0; ni < 4; ni++) {
      int row = wn * 64 + ni * 16 + r16;
      bq[ni] = *(const bf16x8*)(Bd + ((kg * 128 + row) << 4));
    }
#pragma unroll
    for (int mi = 0; mi < 4; mi++)
#pragma unroll
      for (int ni = 0; ni < 4; ni++)
        acc[mi][ni] = __builtin_amdgcn_mfma_f32_16x16x32_bf16(bq[ni], af[mi], acc[mi][ni], 0, 0, 0);
  };

  stageA16(0); stageB(0); stageA16(1); stageB(1);
  asm volatile("s_waitcnt vmcnt(%0)" :: "i"(STEADY) : "memory");
  pipe_barrier();

  auto step = [&](auto TC) {
    constexpr int t = decltype(TC)::v;
    if constexpr (t + 2 < NT) { stageA16(t + 2); stageB(t + 2); }
    compute(t);
    if constexpr (t + 1 < NT) {
      if constexpr (t + 2 < NT)
        asm volatile("s_waitcnt vmcnt(%0)" :: "i"(STEADY) : "memory");
      else
        asm volatile("s_waitcnt vmcnt(0)" ::: "memory");
      pipe_barrier();
    }
  };
  step(IC<0>{}); step(IC<1>{}); step(IC<2>{}); step(IC<3>{});
  step(IC<4>{}); step(IC<5>{}); step(IC<6>{}); step(IC<7>{});

  int rowBase = mt * 128 + wm * 64;
  int colBase = nt * 128 + wn * 64;
#pragma unroll
  for (int ni = 0; ni < 4; ni++) {
    int col = colBase + ni * 16 + kg * 4;
    f32x4 bs = *(const f32x4*)(bias + col);
#pragma unroll
    for (int mi = 0; mi < 4; mi++) {
      int row = rowBase + mi * 16 + r16;
      f32x4 v = acc[mi][ni] + bs;
      *(f32x4*)(C + (size_t)row * N + col) = v;
    }
  }
}

// ---------------- sampling: batched 16-gather MLP + b-locality XCD swizzle -----
// nwg = 2000 = 8*250: XCD k gets 250 consecutive blocks = 2 batches' queries ->
// value[b] (2.8MB/batch, 5.7MB/XCD) becomes mostly L2-resident instead of
// streaming all 44.6MB through every XCD's L2.
__global__ __launch_bounds__(256, 3) void sample_k(const float* __restrict__ offattn, // [MQ,384]
                                                   const float* __restrict__ refp,    // [B,Q,4,2]
                                                   const unsigned short* __restrict__ value,
                                                   unsigned short* __restrict__ interS) {
  int orig = blockIdx.x;
  int sb = (orig & 7) * 250 + (orig >> 3);   // bijective (2000 % 8 == 0)
  int t  = sb * 256 + threadIdx.x;
  int bq = t >> 5;
  int h  = (t >> 2) & 7;
  int c0 = (t & 3) << 3;
  int b  = bq / QQ;

  const float* base = offattn + (size_t)bq * 384;

  float lg[16];
  const float4* ab4 = (const float4*)(base + 256 + h * 16);
#pragma unroll
  for (int i = 0; i < 4; i++) {
    float4 v = ab4[i];
    lg[4*i] = v.x; lg[4*i+1] = v.y; lg[4*i+2] = v.z; lg[4*i+3] = v.w;
  }
  float m = -1e30f;
#pragma unroll
  for (int i = 0; i < 16; i++) m = fmaxf(m, lg[i]);
  float s = 0.f;
#pragma unroll
  for (int i = 0; i < 16; i++) { lg[i] = __expf(lg[i] - m); s += lg[i]; }
  float inv = 1.0f / s;

  float4 r01 = ((const float4*)(refp + (size_t)bq * 8))[0];
  float4 r23 = ((const float4*)(refp + (size_t)bq * 8))[1];
  float rxs[4] = {r01.x, r01.z, r23.x, r23.z};
  float rys[4] = {r01.y, r01.w, r23.y, r23.w};

  const unsigned short* vb = value + (size_t)b * (LTOTAL * 256) + h * 32 + c0;
  const int startL[4] = {0, 4096, 5120, 5376};

  float acc[8] = {};
#pragma unroll
  for (int lvl = 0; lvl < 4; lvl++) {
    int   Wi = 64 >> lvl;
    float Wf = (float)Wi;
    float px = rxs[lvl] * Wf - 0.5f;
    float py = rys[lvl] * Wf - 0.5f;
    const unsigned short* vl = vb + (size_t)startL[lvl] * 256;

    const float4* ob4 = (const float4*)(base + h * 32 + lvl * 8);
    float4 o01 = ob4[0], o23 = ob4[1];
    float oxs[4] = {o01.x, o01.z, o23.x, o23.z};
    float oys[4] = {o01.y, o01.w, o23.y, o23.w};

    float cw[16];
    int   coff[16];
#pragma unroll
    for (int pt = 0; pt < 4; pt++) {
      float wa = lg[lvl * 4 + pt] * inv;
      float x = px + oxs[pt];
      float y = py + oys[pt];
      float xf = floorf(x), yf = floorf(y);
      float lx = x - xf, ly = y - yf;
      int x0 = (int)xf, y0 = (int)yf;
      float wx[2] = {1.f - lx, lx};
      float wy[2] = {1.f - ly, ly};
#pragma unroll
      for (int cy = 0; cy < 2; cy++) {
        int Y = y0 + cy;
        bool vy = (unsigned)Y < (unsigned)Wi;
        int Yc = min(max(Y, 0), Wi - 1);
#pragma unroll
        for (int cx = 0; cx < 2; cx++) {
          int X = x0 + cx;
          bool vx = (unsigned)X < (unsigned)Wi;
          int Xc = min(max(X, 0), Wi - 1);
          int c = pt * 4 + cy * 2 + cx;
          cw[c]   = (vx && vy) ? wa * wy[cy] * wx[cx] : 0.f;
          coff[c] = (Yc * Wi + Xc) * 256;
        }
      }
    }
    uint4 raw[16];
#pragma unroll
    for (int c = 0; c < 16; c++) raw[c] = *(const uint4*)(vl + coff[c]);
#pragma unroll
    for (int c = 0; c < 16; c++) {
      float w = cw[c];
      acc[0] += w * b2f_lo(raw[c].x); acc[1] += w * b2f_hi(raw[c].x);
      acc[2] += w * b2f_lo(raw[c].y); acc[3] += w * b2f_hi(raw[c].y);
      acc[4] += w * b2f_lo(raw[c].z); acc[5] += w * b2f_hi(raw[c].z);
      acc[6] += w * b2f_lo(raw[c].w); acc[7] += w * b2f_hi(raw[c].w);
    }
  }

  unsigned o0 = f2bf(acc[0]) | ((unsigned)f2bf(acc[1]) << 16);
  unsigned o1 = f2bf(acc[2]) | ((unsigned)f2bf(acc[3]) << 16);
  unsigned o2 = f2bf(acc[4]) | ((unsigned)f2bf(acc[5]) << 16);
  unsigned o3 = f2bf(acc[6]) | ((unsigned)f2bf(acc[7]) << 16);
  uint4 st = {o0, o1, o2, o3};

  // staged layout: tile = bq>>7, row = bq&127, stage = h, u = c0>>3
  int mtile = bq >> 7, row = bq & 127;
  size_t goff = (((size_t)(mtile * 8 + h)) * 512 + (c0 >> 3) * 128 + row) * 8;
  *(uint4*)(interS + goff) = st;
}

extern "C" void kernel_launch(void* const* d_in, const int* in_sizes, int n_in,
                              void* d_out, int out_size, void* d_ws, size_t ws_size,
                              hipStream_t stream) {
  const float* query  = (const float*)d_in[0];
  const float* refp   = (const float*)d_in[1];
  const float* inputf = (const float*)d_in[2];
  const float* Wv   = (const float*)d_in[5];
  const float* bv   = (const float*)d_in[6];
  const float* Wo   = (const float*)d_in[7];
  const float* bo   = (const float*)d_in[8];
  const float* Wa   = (const float*)d_in[9];
  const float* ba   = (const float*)d_in[10];
  const float* Wout = (const float*)d_in[11];
  const float* bout = (const float*)d_in[12];

  char* p = (char*)d_ws;
  auto alloc = [&](size_t bytes) -> char* {
    char* r = p;
    p += (bytes + 255) & ~(size_t)255;
    return r;
  };
  unsigned short* val   = (unsigned short*)alloc((size_t)MV * 256 * 2);
  unsigned short* WvS   = (unsigned short*)alloc(2 * 4096 * 8 * 2);
  unsigned short* WcS   = (unsigned short*)alloc(3 * 4096 * 8 * 2);
  unsigned short* WoS   = (unsigned short*)alloc(2 * 4096 * 8 * 2);
  float*          bcat  = (float*)alloc(384 * 4);
  float*          offattn = (float*)alloc((size_t)MQ * 384 * 4);
  unsigned short* interS = (unsigned short*)alloc((size_t)MQ * 256 * 2);

  prep_k<<<114, 256, 0, stream>>>(Wv, Wo, Wa, Wout, bo, ba, WvS, WcS, WoS, bcat);

  // fused: value GEMM (1360 blocks) + offattn GEMM (375 blocks), one dispatch
  gemmf_k<<<NVBLK + NOBLK, 256, 0, stream>>>(inputf, query, WvS, WcS, bv, bcat,
                                             val, offattn);
  // sampling -> interS (staged bf16), b-locality XCD swizzle
  sample_k<<<MQ * 32 / 256, 256, 0, stream>>>(offattn, refp, val, interS);
  // out = interS @ Wout + bout -> fp32 d_out
  gemm3b_k<<<(MQ / 128) * 2, 256, 0, stream>>>(interS, WoS, bout, (float*)d_out,
                                               MQ, 256);
}